// Round 1
// baseline (1949.250 us; speedup 1.0000x reference)
//
#include <hip/hip_runtime.h>
#include <cstddef>

// Problem constants
#define QN   200
#define BN   8
#define DIM  512
#define NHEAD 8
#define HD   64
#define C2   256
#define NH2  4
#define NTOK 4096   // 64*64
#define SCALE 0.125f

// ---------------------------------------------------------------------------
// Weight transpose: w (512, 512, KK) -> wt (512, KK*512) with k' = p*512+ci
// One block per output channel c. Coalesced read + coalesced write via LDS.
// ---------------------------------------------------------------------------
__global__ __launch_bounds__(256) void wtrans_kernel(
    const float* __restrict__ w, float* __restrict__ wt, int KK, int lKK)
{
    __shared__ float tile[512 * 17];  // max KK=16, pad stride KK+1
    const int c = blockIdx.x;
    const int K = KK << 9;
    const float* src = w + (size_t)c * K;
    float* dst = wt + (size_t)c * K;
    for (int i = threadIdx.x; i < K; i += 256) {
        int ci = i >> lKK, p = i & (KK - 1);
        tile[ci * (KK + 1) + p] = src[i];
    }
    __syncthreads();
    for (int i = threadIdx.x; i < K; i += 256) {
        int p = i >> 9, ci = i & 511;
        dst[i] = tile[ci * (KK + 1) + p];
    }
}

// ---------------------------------------------------------------------------
// Generic tiled GEMM: C(M,N) = A(M,K) * B(N,K)^T + bias(N)
// MODE 0: A is plain row-major (M,K).
// MODE 1: A is gathered conv patches from key/value (B,4096,512):
//         row m = (b, oy, ox), k' = p*512 + ci, p = ky*s + kx,
//         element = img[b, (s*oy+ky)*64 + s*ox+kx, ci]
// 64x64 tile, BK=16, 256 threads, 4x4 per thread, reg-prefetch pipeline.
// ---------------------------------------------------------------------------
template <int MODE>
__global__ __launch_bounds__(256) void gemm_nt(
    const float* __restrict__ Ap, const float* __restrict__ Bp,
    const float* __restrict__ bias, float* __restrict__ Cp,
    int M, int N, int K, int lOW, int ls)
{
    __shared__ float As[16][68];
    __shared__ float Bs[16][68];
    const int tid = threadIdx.x;
    const int m0 = blockIdx.y * 64;
    const int n0 = blockIdx.x * 64;
    const int lr  = tid >> 2;        // 0..63 row within tile
    const int lc4 = (tid & 3) * 4;   // 0,4,8,12

    const float* a_base = nullptr;
    int conv_bn_base = 0;
    if constexpr (MODE == 0) {
        a_base = Ap + (size_t)(m0 + lr) * K;
    } else {
        const int OW = 1 << lOW;
        const int a_m = m0 + lr;
        const int bidx = a_m >> (2 * lOW);
        const int pix  = a_m & (OW * OW - 1);
        const int oy = pix >> lOW;
        const int ox = pix & (OW - 1);
        conv_bn_base = bidx * NTOK + ((oy << ls) * 64 + (ox << ls));
    }
    const float* b_base = Bp + (size_t)(n0 + lr) * K;

    auto loadA = [&](int k0) -> float4 {
        if constexpr (MODE == 0) {
            return *(const float4*)(a_base + k0 + lc4);
        } else {
            const int p  = k0 >> 9;
            const int ci = (k0 & 511) + lc4;
            const int ky = p >> ls;
            const int kx = p & ((1 << ls) - 1);
            const int n = conv_bn_base + ky * 64 + kx;
            return *(const float4*)(Ap + ((size_t)n << 9) + ci);
        }
    };

    float acc[4][4] = {};
    const int ty = tid >> 4, tx = tid & 15;

    float4 areg = loadA(0);
    float4 breg = *(const float4*)(b_base + lc4);
    const int ktiles = K >> 4;
    for (int t = 0; t < ktiles; ++t) {
        As[lc4 + 0][lr] = areg.x; As[lc4 + 1][lr] = areg.y;
        As[lc4 + 2][lr] = areg.z; As[lc4 + 3][lr] = areg.w;
        Bs[lc4 + 0][lr] = breg.x; Bs[lc4 + 1][lr] = breg.y;
        Bs[lc4 + 2][lr] = breg.z; Bs[lc4 + 3][lr] = breg.w;
        __syncthreads();
        if (t + 1 < ktiles) {
            const int k0 = (t + 1) << 4;
            areg = loadA(k0);
            breg = *(const float4*)(b_base + k0 + lc4);
        }
#pragma unroll
        for (int kk = 0; kk < 16; ++kk) {
            const float4 av = *(const float4*)&As[kk][ty * 4];
            const float4 bv = *(const float4*)&Bs[kk][tx * 4];
            const float a[4] = {av.x, av.y, av.z, av.w};
            const float bb[4] = {bv.x, bv.y, bv.z, bv.w};
#pragma unroll
            for (int i = 0; i < 4; ++i)
#pragma unroll
                for (int j = 0; j < 4; ++j)
                    acc[i][j] = fmaf(a[i], bb[j], acc[i][j]);
        }
        __syncthreads();
    }

    const int cm = m0 + ty * 4;
    const int cn = n0 + tx * 4;
#pragma unroll
    for (int i = 0; i < 4; ++i) {
        float4 o;
        o.x = acc[i][0]; o.y = acc[i][1]; o.z = acc[i][2]; o.w = acc[i][3];
        if (bias) {
            o.x += bias[cn + 0]; o.y += bias[cn + 1];
            o.z += bias[cn + 2]; o.w += bias[cn + 3];
        }
        *(float4*)(Cp + (size_t)(cm + i) * N + cn) = o;
    }
}

// ---------------------------------------------------------------------------
// Fused LayerNorm (over C=512) + ReLU6, in place. 4 rows / block (wave/row).
// ---------------------------------------------------------------------------
__global__ __launch_bounds__(256) void ln_relu6_kernel(
    float* __restrict__ buf, const float* __restrict__ g,
    const float* __restrict__ bta)
{
    const int row = blockIdx.x * 4 + (threadIdx.x >> 6);
    const int lane = threadIdx.x & 63;
    float* p = buf + (size_t)row * DIM;
    float v[8];
    float s1 = 0.f, s2 = 0.f;
#pragma unroll
    for (int j = 0; j < 8; ++j) {
        v[j] = p[lane + 64 * j];
        s1 += v[j];
        s2 += v[j] * v[j];
    }
#pragma unroll
    for (int off = 32; off; off >>= 1) {
        s1 += __shfl_xor(s1, off, 64);
        s2 += __shfl_xor(s2, off, 64);
    }
    const float mean = s1 * (1.0f / DIM);
    const float var = s2 * (1.0f / DIM) - mean * mean;
    const float rstd = rsqrtf(var + 1e-5f);
#pragma unroll
    for (int j = 0; j < 8; ++j) {
        const int c = lane + 64 * j;
        float y = (v[j] - mean) * rstd * g[c] + bta[c];
        p[c] = fminf(fmaxf(y, 0.0f), 6.0f);
    }
}

// ---------------------------------------------------------------------------
// vplus = v + dwconv3x3(v viewed as (B,C2,OW,OW)) + bias. One thread/element.
// ---------------------------------------------------------------------------
__global__ __launch_bounds__(256) void vplus_kernel(
    const float* __restrict__ vbuf, const float* __restrict__ lw,
    const float* __restrict__ lb, float* __restrict__ out, int lOW, int lL)
{
    const int idx = blockIdx.x * 256 + threadIdx.x;
    const int c = idx & 255;
    const int pix = (idx >> 8) & ((1 << lL) - 1);
    const int b = idx >> (8 + lL);
    const int OW = 1 << lOW;
    const int y = pix >> lOW, x = pix & (OW - 1);
    float acc = lb[c];
#pragma unroll
    for (int dy = -1; dy <= 1; ++dy) {
        const int ny = y + dy;
        if ((unsigned)ny >= (unsigned)OW) continue;
#pragma unroll
        for (int dx = -1; dx <= 1; ++dx) {
            const int nx = x + dx;
            if ((unsigned)nx >= (unsigned)OW) continue;
            acc += vbuf[(((size_t)(b << lL) + ny * OW + nx) << 8) + c] *
                   lw[c * 9 + (dy + 1) * 3 + (dx + 1)];
        }
    }
    out[idx] = vbuf[idx] + acc;
}

// ---------------------------------------------------------------------------
// Attention: one block per (b, h, 8-query tile). Full softmax row in LDS.
// q[b,h,qi,d] = qbuf[((b*200+qi)*8 + hoff+h)*64 + d]  (raw-reshape layout)
// k,v: (B*L, 256) row-major, head h at column h*64.
// Output written into xbuf (1600,512) at the raw-reshape concat position.
// ---------------------------------------------------------------------------
__global__ __launch_bounds__(256) void attn_kernel(
    const float* __restrict__ qbuf, const float* __restrict__ kbuf,
    const float* __restrict__ vbuf, float* __restrict__ xbuf,
    int L, int hoff, int coff)
{
    __shared__ float q_s[8][64];
    __shared__ float pr[8][1024];
    const int tid = threadIdx.x;
    const int qt = blockIdx.x;   // 0..24
    const int h = blockIdx.y;    // 0..3
    const int b = blockIdx.z;    // 0..7
    const int qi0 = qt * 8;

    for (int i = tid; i < 512; i += 256) {
        const int ql = i >> 6, d = i & 63;
        q_s[ql][d] = qbuf[((size_t)(b * QN + qi0 + ql) * NHEAD + hoff + h) * HD + d];
    }
    __syncthreads();

    // logits
    for (int l = tid; l < L; l += 256) {
        const float* kr = kbuf + ((size_t)(b * L + l)) * C2 + h * HD;
        float acc[8] = {0, 0, 0, 0, 0, 0, 0, 0};
        for (int d = 0; d < 64; d += 4) {
            const float4 kv = *(const float4*)(kr + d);
#pragma unroll
            for (int ql = 0; ql < 8; ++ql) {
                acc[ql] += kv.x * q_s[ql][d] + kv.y * q_s[ql][d + 1] +
                           kv.z * q_s[ql][d + 2] + kv.w * q_s[ql][d + 3];
            }
        }
#pragma unroll
        for (int ql = 0; ql < 8; ++ql) pr[ql][l] = acc[ql] * SCALE;
    }
    __syncthreads();

    // softmax: 8 rows, 32 threads each
    {
        const int row = tid >> 5;
        const int l32 = tid & 31;
        float m = -1e30f;
        for (int l = l32; l < L; l += 32) m = fmaxf(m, pr[row][l]);
#pragma unroll
        for (int off = 16; off; off >>= 1) m = fmaxf(m, __shfl_xor(m, off, 32));
        float s = 0.f;
        for (int l = l32; l < L; l += 32) {
            const float e = __expf(pr[row][l] - m);
            pr[row][l] = e;
            s += e;
        }
#pragma unroll
        for (int off = 16; off; off >>= 1) s += __shfl_xor(s, off, 32);
        const float inv = 1.0f / s;
        for (int l = l32; l < L; l += 32) pr[row][l] *= inv;
    }
    __syncthreads();

    // PV: thread handles (d = tid&63) for queries w and w+4
    const int d = tid & 63;
    const int w = tid >> 6;  // 0..3, uniform per wave
    float acc0 = 0.f, acc1 = 0.f;
    const float* vb = vbuf + ((size_t)(b * L)) * C2 + h * HD + d;
#pragma unroll 4
    for (int l = 0; l < L; ++l) {
        const float v = vb[(size_t)l * C2];
        acc0 += pr[w][l] * v;
        acc1 += pr[w + 4][l] * v;
    }
    {
        const int flat0 = ((b * QN + qi0 + w) * NH2 + h) * HD + d;
        xbuf[(size_t)(flat0 >> 8) * DIM + coff + (flat0 & 255)] = acc0;
        const int flat1 = ((b * QN + qi0 + w + 4) * NH2 + h) * HD + d;
        xbuf[(size_t)(flat1 >> 8) * DIM + coff + (flat1 & 255)] = acc1;
    }
}

// ---------------------------------------------------------------------------
// Launcher
// ---------------------------------------------------------------------------
extern "C" void kernel_launch(void* const* d_in, const int* in_sizes, int n_in,
                              void* d_out, int out_size, void* d_ws, size_t ws_size,
                              hipStream_t stream)
{
    const float* query   = (const float*)d_in[0];
    const float* key     = (const float*)d_in[1];
    const float* value   = (const float*)d_in[2];
    const float* q_w     = (const float*)d_in[3];
    const float* sr1_1_w = (const float*)d_in[4];
    const float* sr1_1_b = (const float*)d_in[5];
    const float* n1_1_g  = (const float*)d_in[6];
    const float* n1_1_b  = (const float*)d_in[7];
    const float* sr1_2_w = (const float*)d_in[8];
    const float* sr1_2_b = (const float*)d_in[9];
    const float* n1_2_g  = (const float*)d_in[10];
    const float* n1_2_b  = (const float*)d_in[11];
    const float* sr2_1_w = (const float*)d_in[12];
    const float* sr2_1_b = (const float*)d_in[13];
    const float* n2_1_g  = (const float*)d_in[14];
    const float* n2_1_b  = (const float*)d_in[15];
    const float* sr2_2_w = (const float*)d_in[16];
    const float* sr2_2_b = (const float*)d_in[17];
    const float* n2_2_g  = (const float*)d_in[18];
    const float* n2_2_b  = (const float*)d_in[19];
    const float* k1_w    = (const float*)d_in[20];
    const float* v1_w    = (const float*)d_in[21];
    const float* k2_w    = (const float*)d_in[22];
    const float* v2_w    = (const float*)d_in[23];
    const float* lc1_w   = (const float*)d_in[24];
    const float* lc1_b   = (const float*)d_in[25];
    const float* lc2_w   = (const float*)d_in[26];
    const float* lc2_b   = (const float*)d_in[27];
    const float* proj_w  = (const float*)d_in[28];
    const float* proj_b  = (const float*)d_in[29];
    float* out = (float*)d_out;
    float* ws = (float*)d_ws;

    // workspace offsets (floats). Wt region is reused for qbuf..xbuf after convs.
    const size_t WT1K = 0;                    // 512*8192
    const size_t WT1V = WT1K + 4194304;
    const size_t WT2K = WT1V + 4194304;       // 512*2048
    const size_t WT2V = WT2K + 1048576;
    const size_t QBUF = 0;                    // 1600*512  (reuses Wt region)
    const size_t K1   = QBUF + 819200;        // 2048*256
    const size_t V1   = K1 + 524288;
    const size_t K2   = V1 + 524288;          // 8192*256
    const size_t V2   = K2 + 2097152;
    const size_t VP1  = V2 + 2097152;         // 2048*256
    const size_t VP2  = VP1 + 524288;         // 8192*256
    const size_t XBUF = VP2 + 2097152;        // 1600*512 -> ends 9502720 < 10485760 OK
    const size_t KEY1 = WT2V + 1048576;       // 2048*512
    const size_t VAL1 = KEY1 + 1048576;
    const size_t KEY2 = VAL1 + 1048576;       // 8192*512
    const size_t VAL2 = KEY2 + 4194304;       // ends 20971520 floats = 80 MB

    // 1) transpose conv weights to (c, p*512+ci)
    wtrans_kernel<<<512, 256, 0, stream>>>(sr1_1_w, ws + WT1K, 16, 4);
    wtrans_kernel<<<512, 256, 0, stream>>>(sr1_2_w, ws + WT1V, 16, 4);
    wtrans_kernel<<<512, 256, 0, stream>>>(sr2_1_w, ws + WT2K, 4, 2);
    wtrans_kernel<<<512, 256, 0, stream>>>(sr2_2_w, ws + WT2V, 4, 2);

    // 2) patchify convs as GEMM (output (B*L, 512) + bias)
    gemm_nt<1><<<dim3(8, 32), 256, 0, stream>>>(key,   ws + WT1K, sr1_1_b, ws + KEY1, 2048, 512, 8192, 4, 2);
    gemm_nt<1><<<dim3(8, 32), 256, 0, stream>>>(value, ws + WT1V, sr1_2_b, ws + VAL1, 2048, 512, 8192, 4, 2);
    gemm_nt<1><<<dim3(8, 128), 256, 0, stream>>>(key,   ws + WT2K, sr2_1_b, ws + KEY2, 8192, 512, 2048, 5, 1);
    gemm_nt<1><<<dim3(8, 128), 256, 0, stream>>>(value, ws + WT2V, sr2_2_b, ws + VAL2, 8192, 512, 2048, 5, 1);

    // 3) LayerNorm + ReLU6 in place
    ln_relu6_kernel<<<512, 256, 0, stream>>>(ws + KEY1, n1_1_g, n1_1_b);
    ln_relu6_kernel<<<512, 256, 0, stream>>>(ws + VAL1, n1_2_g, n1_2_b);
    ln_relu6_kernel<<<2048, 256, 0, stream>>>(ws + KEY2, n2_1_g, n2_1_b);
    ln_relu6_kernel<<<2048, 256, 0, stream>>>(ws + VAL2, n2_2_g, n2_2_b);

    // 4) q projection (raw (1600,512) rows)
    gemm_nt<0><<<dim3(8, 25), 256, 0, stream>>>(query, q_w, nullptr, ws + QBUF, 1600, 512, 512, 0, 0);

    // 5) k/v head projections -> (B*L, 256)
    gemm_nt<0><<<dim3(4, 32), 256, 0, stream>>>(ws + KEY1, k1_w, nullptr, ws + K1, 2048, 256, 512, 0, 0);
    gemm_nt<0><<<dim3(4, 32), 256, 0, stream>>>(ws + VAL1, v1_w, nullptr, ws + V1, 2048, 256, 512, 0, 0);
    gemm_nt<0><<<dim3(4, 128), 256, 0, stream>>>(ws + KEY2, k2_w, nullptr, ws + K2, 8192, 256, 512, 0, 0);
    gemm_nt<0><<<dim3(4, 128), 256, 0, stream>>>(ws + VAL2, v2_w, nullptr, ws + V2, 8192, 256, 512, 0, 0);

    // 6) v + local dwconv
    vplus_kernel<<<2048, 256, 0, stream>>>(ws + V1, lc1_w, lc1_b, ws + VP1, 4, 8);
    vplus_kernel<<<8192, 256, 0, stream>>>(ws + V2, lc2_w, lc2_b, ws + VP2, 5, 10);

    // 7) attention, both branches, writes into xbuf (1600,512)
    attn_kernel<<<dim3(25, 4, 8), 256, 0, stream>>>(ws + QBUF, ws + K1, ws + VP1, ws + XBUF, 256, 0, 0);
    attn_kernel<<<dim3(25, 4, 8), 256, 0, stream>>>(ws + QBUF, ws + K2, ws + VP2, ws + XBUF, 1024, 4, 256);

    // 8) final projection + bias -> d_out (200,8,512)
    gemm_nt<0><<<dim3(8, 25), 256, 0, stream>>>(ws + XBUF, proj_w, proj_b, out, 1600, 512, 512, 0, 0);
}

// Round 2
// 1064.784 us; speedup vs baseline: 1.8307x; 1.8307x over previous
//
#include <hip/hip_runtime.h>
#include <cstddef>

// Problem constants
#define QN   200
#define DIM  512
#define NHEAD 8
#define HD   64
#define C2   256
#define NH2  4
#define NTOK 4096   // 64*64
#define SCALE 0.125f

typedef short s16x8 __attribute__((ext_vector_type(8)));   // 8 bf16 (4 VGPRs)
typedef float f32x4 __attribute__((ext_vector_type(4)));   // MFMA accumulator

__device__ __forceinline__ unsigned short f2bf(float f) {
    unsigned int u = __float_as_uint(f);
    u += 0x7fffu + ((u >> 16) & 1u);   // round-to-nearest-even
    return (unsigned short)(u >> 16);
}

__device__ __forceinline__ s16x8 pack8(float4 x, float4 y) {
    s16x8 v;
    v[0] = (short)f2bf(x.x); v[1] = (short)f2bf(x.y);
    v[2] = (short)f2bf(x.z); v[3] = (short)f2bf(x.w);
    v[4] = (short)f2bf(y.x); v[5] = (short)f2bf(y.y);
    v[6] = (short)f2bf(y.z); v[7] = (short)f2bf(y.w);
    return v;
}

// ---------------------------------------------------------------------------
// Weight transpose: w (512, 512, KK) -> wt (512, KK*512) with k' = p*512+ci
// ---------------------------------------------------------------------------
__global__ __launch_bounds__(256) void wtrans_kernel(
    const float* __restrict__ w, float* __restrict__ wt, int KK, int lKK)
{
    __shared__ float tile[512 * 17];
    const int c = blockIdx.x;
    const int K = KK << 9;
    const float* src = w + (size_t)c * K;
    float* dst = wt + (size_t)c * K;
    for (int i = threadIdx.x; i < K; i += 256) {
        int ci = i >> lKK, p = i & (KK - 1);
        tile[ci * (KK + 1) + p] = src[i];
    }
    __syncthreads();
    for (int i = threadIdx.x; i < K; i += 256) {
        int p = i >> 9, ci = i & 511;
        dst[i] = tile[ci * (KK + 1) + p];
    }
}

// ---------------------------------------------------------------------------
// MFMA bf16 GEMM: C(M,N) = A(M,K) * B(N,K)^T (+bias)
// CONV=0: A plain fp32 row-major.  CONV=1: A gathered conv patches (fp32).
// fp32 global loads -> in-register bf16 pack -> LDS (padded) -> 16x16x32 MFMA.
// 256 threads = 4 waves (2x2); wave tile (BM/2)x(BN/2). BK=32.
// gridDim.z = split-K count; partial z written to Cp + z*M*N (no bias).
// ---------------------------------------------------------------------------
template <int BM, int BN, int CONV>
__global__ __launch_bounds__(256) void mfma_gemm(
    const float* __restrict__ Ap, const float* __restrict__ Bp,
    const float* __restrict__ bias, float* __restrict__ Cp,
    int M, int N, int K, int klen, int lOW, int ls)
{
    constexpr int LDA = 40;                 // 32 + 8 pad (80 B row stride)
    constexpr int IA = (BM * 4) / 256;      // 8-elem groups per thread (A)
    constexpr int IB = (BN * 4) / 256;
    constexpr int FM = BM / 32;             // 16x16 frags per wave (M)
    constexpr int FN = BN / 32;
    __shared__ alignas(16) short As[BM][LDA];
    __shared__ alignas(16) short Bs[BN][LDA];

    const int tid = threadIdx.x;
    const int m0 = blockIdx.y * BM;
    const int n0 = blockIdx.x * BN;
    const int kstart = blockIdx.z * klen;
    float* __restrict__ Cpe = Cp + (size_t)blockIdx.z * M * N;

    const int lane = tid & 63;
    const int quad = lane >> 4;
    const int l16 = lane & 15;
    const int wave = tid >> 6;
    const int wm = (wave >> 1) * (BM / 2);
    const int wn = (wave & 1) * (BN / 2);

    // staging maps: group g covers LDS row g>>2, cols (g&3)*8 .. +7
    int ar[IA], ac[IA];
    size_t abase[IA];
#pragma unroll
    for (int i = 0; i < IA; ++i) {
        const int g = tid + i * 256;
        ar[i] = g >> 2;
        ac[i] = (g & 3) * 8;
        if constexpr (CONV) {
            const int OW = 1 << lOW;
            const int m = m0 + ar[i];
            const int bidx = m >> (2 * lOW);
            const int pix = m & (OW * OW - 1);
            const int oy = pix >> lOW, ox = pix & (OW - 1);
            abase[i] = (size_t)(bidx * NTOK + (oy << ls) * 64 + (ox << ls)) << 9;
        } else {
            abase[i] = (size_t)(m0 + ar[i]) * K;
        }
    }
    int br[IB], bc[IB];
    size_t bbase[IB];
#pragma unroll
    for (int i = 0; i < IB; ++i) {
        const int g = tid + i * 256;
        br[i] = g >> 2;
        bc[i] = (g & 3) * 8;
        bbase[i] = (size_t)(n0 + br[i]) * K;
    }

    float4 axr[IA], ayr[IA], bxr[IB], byr[IB];
    auto load_t = [&](int t) {
        const int k = kstart + t * 32;
#pragma unroll
        for (int i = 0; i < IA; ++i) {
            size_t o;
            if constexpr (CONV) {
                const int p = k >> 9;
                const int ky = p >> ls, kx = p & ((1 << ls) - 1);
                o = abase[i] + ((size_t)(ky * 64 + kx) << 9) + (k & 511) + ac[i];
            } else {
                o = abase[i] + k + ac[i];
            }
            axr[i] = *(const float4*)(Ap + o);
            ayr[i] = *(const float4*)(Ap + o + 4);
        }
#pragma unroll
        for (int i = 0; i < IB; ++i) {
            const size_t o = bbase[i] + k + bc[i];
            bxr[i] = *(const float4*)(Bp + o);
            byr[i] = *(const float4*)(Bp + o + 4);
        }
    };

    f32x4 acc[FM][FN];
#pragma unroll
    for (int a = 0; a < FM; ++a)
#pragma unroll
        for (int b = 0; b < FN; ++b)
            acc[a][b] = (f32x4){0.f, 0.f, 0.f, 0.f};

    load_t(0);
    const int nk = klen >> 5;
    for (int t = 0; t < nk; ++t) {
        __syncthreads();
#pragma unroll
        for (int i = 0; i < IA; ++i)
            *(s16x8*)&As[ar[i]][ac[i]] = pack8(axr[i], ayr[i]);
#pragma unroll
        for (int i = 0; i < IB; ++i)
            *(s16x8*)&Bs[br[i]][bc[i]] = pack8(bxr[i], byr[i]);
        __syncthreads();
        if (t + 1 < nk) load_t(t + 1);

        s16x8 af[FM], bfv[FN];
#pragma unroll
        for (int f = 0; f < FM; ++f)
            af[f] = *(const s16x8*)&As[wm + f * 16 + l16][quad * 8];
#pragma unroll
        for (int f = 0; f < FN; ++f)
            bfv[f] = *(const s16x8*)&Bs[wn + f * 16 + l16][quad * 8];
#pragma unroll
        for (int a = 0; a < FM; ++a)
#pragma unroll
            for (int b = 0; b < FN; ++b)
                acc[a][b] = __builtin_amdgcn_mfma_f32_16x16x32_bf16(
                    af[a], bfv[b], acc[a][b], 0, 0, 0);
    }

    // epilogue: C/D layout col=lane&15, row=quad*4+reg  (m89-verified)
#pragma unroll
    for (int a = 0; a < FM; ++a) {
        const int m = m0 + wm + a * 16 + quad * 4;
#pragma unroll
        for (int b = 0; b < FN; ++b) {
            const int n = n0 + wn + b * 16 + l16;
            const float bv = bias ? bias[n] : 0.f;
#pragma unroll
            for (int r = 0; r < 4; ++r)
                Cpe[(size_t)(m + r) * N + n] = acc[a][b][r] + bv;
        }
    }
}

// ---------------------------------------------------------------------------
// LayerNorm + ReLU6 with fused split-K reduction and conv bias.
// dst(row,512) = relu6(LN(sum_{ip<np} src[ip*pstride + row*512 + c] + cb[c]))
// np=1, src==dst, pstride=0 -> plain in-place LN (+bias). 4 rows/block.
// ---------------------------------------------------------------------------
__global__ __launch_bounds__(256) void ln_relu6_kernel(
    float* __restrict__ dst, const float* __restrict__ src, size_t pstride, int np,
    const float* __restrict__ cb, const float* __restrict__ g,
    const float* __restrict__ bta)
{
    const int row = blockIdx.x * 4 + (threadIdx.x >> 6);
    const int lane = threadIdx.x & 63;
    float v[8];
#pragma unroll
    for (int j = 0; j < 8; ++j) v[j] = cb[lane + 64 * j];
    const float* p = src + (size_t)row * DIM;
    for (int ip = 0; ip < np; ++ip) {
#pragma unroll
        for (int j = 0; j < 8; ++j) v[j] += p[lane + 64 * j];
        p += pstride;
    }
    float s1 = 0.f, s2 = 0.f;
#pragma unroll
    for (int j = 0; j < 8; ++j) { s1 += v[j]; s2 += v[j] * v[j]; }
#pragma unroll
    for (int off = 32; off; off >>= 1) {
        s1 += __shfl_xor(s1, off, 64);
        s2 += __shfl_xor(s2, off, 64);
    }
    const float mean = s1 * (1.0f / DIM);
    const float var = s2 * (1.0f / DIM) - mean * mean;
    const float rstd = rsqrtf(var + 1e-5f);
    float* q = dst + (size_t)row * DIM;
#pragma unroll
    for (int j = 0; j < 8; ++j) {
        const int c = lane + 64 * j;
        float y = (v[j] - mean) * rstd * g[c] + bta[c];
        q[c] = fminf(fmaxf(y, 0.0f), 6.0f);
    }
}

// ---------------------------------------------------------------------------
// vplus = v + dwconv3x3(v viewed as (B,C2,OW,OW)) + bias. One thread/element.
// ---------------------------------------------------------------------------
__global__ __launch_bounds__(256) void vplus_kernel(
    const float* __restrict__ vbuf, const float* __restrict__ lw,
    const float* __restrict__ lb, float* __restrict__ out, int lOW, int lL)
{
    const int idx = blockIdx.x * 256 + threadIdx.x;
    const int c = idx & 255;
    const int pix = (idx >> 8) & ((1 << lL) - 1);
    const int b = idx >> (8 + lL);
    const int OW = 1 << lOW;
    const int y = pix >> lOW, x = pix & (OW - 1);
    float acc = lb[c];
#pragma unroll
    for (int dy = -1; dy <= 1; ++dy) {
        const int ny = y + dy;
        if ((unsigned)ny >= (unsigned)OW) continue;
#pragma unroll
        for (int dx = -1; dx <= 1; ++dx) {
            const int nx = x + dx;
            if ((unsigned)nx >= (unsigned)OW) continue;
            acc += vbuf[(((size_t)(b << lL) + ny * OW + nx) << 8) + c] *
                   lw[c * 9 + (dy + 1) * 3 + (dx + 1)];
        }
    }
    out[idx] = vbuf[idx] + acc;
}

// ---------------------------------------------------------------------------
// Attention (fp32): one block per (b, h, 8-query tile). Softmax row in LDS.
// ---------------------------------------------------------------------------
__global__ __launch_bounds__(256) void attn_kernel(
    const float* __restrict__ qbuf, const float* __restrict__ kbuf,
    const float* __restrict__ vbuf, float* __restrict__ xbuf,
    int L, int hoff, int coff)
{
    __shared__ float q_s[8][64];
    __shared__ float pr[8][1024];
    const int tid = threadIdx.x;
    const int qt = blockIdx.x;
    const int h = blockIdx.y;
    const int b = blockIdx.z;
    const int qi0 = qt * 8;

    for (int i = tid; i < 512; i += 256) {
        const int ql = i >> 6, d = i & 63;
        q_s[ql][d] = qbuf[((size_t)(b * QN + qi0 + ql) * NHEAD + hoff + h) * HD + d];
    }
    __syncthreads();

    for (int l = tid; l < L; l += 256) {
        const float* kr = kbuf + ((size_t)(b * L + l)) * C2 + h * HD;
        float acc[8] = {0, 0, 0, 0, 0, 0, 0, 0};
        for (int d = 0; d < 64; d += 4) {
            const float4 kv = *(const float4*)(kr + d);
#pragma unroll
            for (int ql = 0; ql < 8; ++ql) {
                acc[ql] += kv.x * q_s[ql][d] + kv.y * q_s[ql][d + 1] +
                           kv.z * q_s[ql][d + 2] + kv.w * q_s[ql][d + 3];
            }
        }
#pragma unroll
        for (int ql = 0; ql < 8; ++ql) pr[ql][l] = acc[ql] * SCALE;
    }
    __syncthreads();

    {
        const int row = tid >> 5;
        const int l32 = tid & 31;
        float m = -1e30f;
        for (int l = l32; l < L; l += 32) m = fmaxf(m, pr[row][l]);
#pragma unroll
        for (int off = 16; off; off >>= 1) m = fmaxf(m, __shfl_xor(m, off, 32));
        float s = 0.f;
        for (int l = l32; l < L; l += 32) {
            const float e = __expf(pr[row][l] - m);
            pr[row][l] = e;
            s += e;
        }
#pragma unroll
        for (int off = 16; off; off >>= 1) s += __shfl_xor(s, off, 32);
        const float inv = 1.0f / s;
        for (int l = l32; l < L; l += 32) pr[row][l] *= inv;
    }
    __syncthreads();

    const int d = tid & 63;
    const int w = tid >> 6;
    float acc0 = 0.f, acc1 = 0.f;
    const float* vb = vbuf + ((size_t)(b * L)) * C2 + h * HD + d;
#pragma unroll 4
    for (int l = 0; l < L; ++l) {
        const float v = vb[(size_t)l * C2];
        acc0 += pr[w][l] * v;
        acc1 += pr[w + 4][l] * v;
    }
    {
        const int flat0 = ((b * QN + qi0 + w) * NH2 + h) * HD + d;
        xbuf[(size_t)(flat0 >> 8) * DIM + coff + (flat0 & 255)] = acc0;
        const int flat1 = ((b * QN + qi0 + w + 4) * NH2 + h) * HD + d;
        xbuf[(size_t)(flat1 >> 8) * DIM + coff + (flat1 & 255)] = acc1;
    }
}

// ---------------------------------------------------------------------------
// Launcher
// ---------------------------------------------------------------------------
extern "C" void kernel_launch(void* const* d_in, const int* in_sizes, int n_in,
                              void* d_out, int out_size, void* d_ws, size_t ws_size,
                              hipStream_t stream)
{
    const float* query   = (const float*)d_in[0];
    const float* key     = (const float*)d_in[1];
    const float* value   = (const float*)d_in[2];
    const float* q_w     = (const float*)d_in[3];
    const float* sr1_1_w = (const float*)d_in[4];
    const float* sr1_1_b = (const float*)d_in[5];
    const float* n1_1_g  = (const float*)d_in[6];
    const float* n1_1_b  = (const float*)d_in[7];
    const float* sr1_2_w = (const float*)d_in[8];
    const float* sr1_2_b = (const float*)d_in[9];
    const float* n1_2_g  = (const float*)d_in[10];
    const float* n1_2_b  = (const float*)d_in[11];
    const float* sr2_1_w = (const float*)d_in[12];
    const float* sr2_1_b = (const float*)d_in[13];
    const float* n2_1_g  = (const float*)d_in[14];
    const float* n2_1_b  = (const float*)d_in[15];
    const float* sr2_2_w = (const float*)d_in[16];
    const float* sr2_2_b = (const float*)d_in[17];
    const float* n2_2_g  = (const float*)d_in[18];
    const float* n2_2_b  = (const float*)d_in[19];
    const float* k1_w    = (const float*)d_in[20];
    const float* v1_w    = (const float*)d_in[21];
    const float* k2_w    = (const float*)d_in[22];
    const float* v2_w    = (const float*)d_in[23];
    const float* lc1_w   = (const float*)d_in[24];
    const float* lc1_b   = (const float*)d_in[25];
    const float* lc2_w   = (const float*)d_in[26];
    const float* lc2_b   = (const float*)d_in[27];
    const float* proj_w  = (const float*)d_in[28];
    const float* proj_b  = (const float*)d_in[29];
    float* out = (float*)d_out;
    float* wsf = (float*)d_ws;

    // --- workspace (float offsets); total 20,971,520 floats = 80 MB ---
    float* WT1K = wsf + 0;          // 512*8192  [dead after conv1key]
    float* WT1V = wsf + 4194304;    // 512*8192  [dead after conv1val]
    float* WT2K = wsf + 8388608;    // 512*2048  [dead after conv2key]
    float* WT2V = wsf + 9437184;    // 512*2048  [dead after conv2val]
    float* KEY1 = wsf + 10485760;   // 2048*512
    float* VAL1 = wsf + 11534336;   // 2048*512
    float* KEY2 = wsf + 12582912;   // 8192*512
    float* VAL2 = wsf + 16777216;   // 8192*512  (end 20,971,520)
    // aliases (live only after the regions above are dead):
    float* K1   = wsf + 0;          // 2048*256   in old WT1K
    float* V1   = wsf + 524288;     // 2048*256
    float* VP1  = wsf + 1048576;    // 2048*256
    float* QBUF = wsf + 1572864;    // 1600*512
    float* XBUF = wsf + 2392064;    // 1600*512   (ends 3,211,264 < 4,194,304)
    float* K2   = wsf + 4194304;    // 8192*256   in old WT1V
    float* V2   = wsf + 6291456;    // 8192*256
    float* VP2  = wsf + 8388608;    // 8192*256   in old WT2K+WT2V
    float* SCRK = KEY2;             // split-K scratch (4 x 2048*512), pre-KEY2
    float* SCRV = VAL2;             // split-K scratch, pre-VAL2

    // 1) conv weight transposes (fp32)
    wtrans_kernel<<<512, 256, 0, stream>>>(sr1_1_w, WT1K, 16, 4);
    wtrans_kernel<<<512, 256, 0, stream>>>(sr1_2_w, WT1V, 16, 4);
    wtrans_kernel<<<512, 256, 0, stream>>>(sr2_1_w, WT2K, 4, 2);
    wtrans_kernel<<<512, 256, 0, stream>>>(sr2_2_w, WT2V, 4, 2);

    // 2) conv GEMMs (MFMA bf16) + fused-reduction LN
    // branch1 key: split-K=4 -> scratch, LN sums partials + bias
    mfma_gemm<128, 128, 1><<<dim3(4, 16, 4), 256, 0, stream>>>(
        key, WT1K, nullptr, SCRK, 2048, 512, 8192, 2048, 4, 2);
    ln_relu6_kernel<<<512, 256, 0, stream>>>(KEY1, SCRK, 1048576, 4, sr1_1_b, n1_1_g, n1_1_b);
    mfma_gemm<128, 128, 1><<<dim3(4, 64, 1), 256, 0, stream>>>(
        key, WT2K, nullptr, KEY2, 8192, 512, 2048, 2048, 5, 1);
    ln_relu6_kernel<<<2048, 256, 0, stream>>>(KEY2, KEY2, 0, 1, sr2_1_b, n2_1_g, n2_1_b);
    mfma_gemm<128, 128, 1><<<dim3(4, 16, 4), 256, 0, stream>>>(
        value, WT1V, nullptr, SCRV, 2048, 512, 8192, 2048, 4, 2);
    ln_relu6_kernel<<<512, 256, 0, stream>>>(VAL1, SCRV, 1048576, 4, sr1_2_b, n1_2_g, n1_2_b);
    mfma_gemm<128, 128, 1><<<dim3(4, 64, 1), 256, 0, stream>>>(
        value, WT2V, nullptr, VAL2, 8192, 512, 2048, 2048, 5, 1);
    ln_relu6_kernel<<<2048, 256, 0, stream>>>(VAL2, VAL2, 0, 1, sr2_2_b, n2_2_g, n2_2_b);

    // 3) q projection
    mfma_gemm<64, 64, 0><<<dim3(8, 25, 1), 256, 0, stream>>>(
        query, q_w, nullptr, QBUF, 1600, 512, 512, 512, 0, 0);

    // 4) k/v head projections
    mfma_gemm<64, 64, 0><<<dim3(4, 32, 1), 256, 0, stream>>>(
        KEY1, k1_w, nullptr, K1, 2048, 256, 512, 512, 0, 0);
    mfma_gemm<64, 64, 0><<<dim3(4, 32, 1), 256, 0, stream>>>(
        VAL1, v1_w, nullptr, V1, 2048, 256, 512, 512, 0, 0);
    mfma_gemm<64, 64, 0><<<dim3(4, 128, 1), 256, 0, stream>>>(
        KEY2, k2_w, nullptr, K2, 8192, 256, 512, 512, 0, 0);
    mfma_gemm<64, 64, 0><<<dim3(4, 128, 1), 256, 0, stream>>>(
        VAL2, v2_w, nullptr, V2, 8192, 256, 512, 512, 0, 0);

    // 5) v + local dwconv
    vplus_kernel<<<2048, 256, 0, stream>>>(V1, lc1_w, lc1_b, VP1, 4, 8);
    vplus_kernel<<<8192, 256, 0, stream>>>(V2, lc2_w, lc2_b, VP2, 5, 10);

    // 6) attention
    attn_kernel<<<dim3(25, 4, 8), 256, 0, stream>>>(QBUF, K1, VP1, XBUF, 256, 0, 0);
    attn_kernel<<<dim3(25, 4, 8), 256, 0, stream>>>(QBUF, K2, VP2, XBUF, 1024, 4, 256);

    // 7) final projection + bias
    mfma_gemm<64, 64, 0><<<dim3(8, 25, 1), 256, 0, stream>>>(
        XBUF, proj_w, proj_b, out, 1600, 512, 512, 512, 0, 0);
}

// Round 3
// 711.853 us; speedup vs baseline: 2.7383x; 1.4958x over previous
//
#include <hip/hip_runtime.h>
#include <cstddef>

// Problem constants
#define QN   200
#define DIM  512
#define NHEAD 8
#define HD   64
#define C2   256
#define NH2  4
#define NTOK 4096   // 64*64

typedef short s16x4 __attribute__((ext_vector_type(4)));
typedef short s16x8 __attribute__((ext_vector_type(8)));   // 8 bf16 (4 VGPRs)
typedef float f32x4 __attribute__((ext_vector_type(4)));   // MFMA accumulator

__device__ __forceinline__ unsigned short f2bf(float f) {
    unsigned int u = __float_as_uint(f);
    u += 0x7fffu + ((u >> 16) & 1u);   // round-to-nearest-even
    return (unsigned short)(u >> 16);
}

__device__ __forceinline__ s16x8 pack8(float4 x, float4 y) {
    s16x8 v;
    v[0] = (short)f2bf(x.x); v[1] = (short)f2bf(x.y);
    v[2] = (short)f2bf(x.z); v[3] = (short)f2bf(x.w);
    v[4] = (short)f2bf(y.x); v[5] = (short)f2bf(y.y);
    v[6] = (short)f2bf(y.z); v[7] = (short)f2bf(y.w);
    return v;
}

// ---------------------------------------------------------------------------
// Weight transpose: w (512, 512, KK) -> wt (512, KK*512) with k' = p*512+ci
// ---------------------------------------------------------------------------
__global__ __launch_bounds__(256) void wtrans_kernel(
    const float* __restrict__ w, float* __restrict__ wt, int KK, int lKK)
{
    __shared__ float tile[512 * 17];
    const int c = blockIdx.x;
    const int K = KK << 9;
    const float* src = w + (size_t)c * K;
    float* dst = wt + (size_t)c * K;
    for (int i = threadIdx.x; i < K; i += 256) {
        int ci = i >> lKK, p = i & (KK - 1);
        tile[ci * (KK + 1) + p] = src[i];
    }
    __syncthreads();
    for (int i = threadIdx.x; i < K; i += 256) {
        int p = i >> 9, ci = i & 511;
        dst[i] = tile[ci * (KK + 1) + p];
    }
}

// ---------------------------------------------------------------------------
// MFMA bf16 GEMM: C(M,N) = A(M,K) * B(N,K)^T (+bias)
// CONV=0: A plain fp32 row-major.  CONV=1: A gathered conv patches (fp32).
// ---------------------------------------------------------------------------
template <int BM, int BN, int CONV>
__global__ __launch_bounds__(256) void mfma_gemm(
    const float* __restrict__ Ap, const float* __restrict__ Bp,
    const float* __restrict__ bias, float* __restrict__ Cp,
    int M, int N, int K, int klen, int lOW, int ls)
{
    constexpr int LDA = 40;
    constexpr int IA = (BM * 4) / 256;
    constexpr int IB = (BN * 4) / 256;
    constexpr int FM = BM / 32;
    constexpr int FN = BN / 32;
    __shared__ alignas(16) short As[BM][LDA];
    __shared__ alignas(16) short Bs[BN][LDA];

    const int tid = threadIdx.x;
    const int m0 = blockIdx.y * BM;
    const int n0 = blockIdx.x * BN;
    const int kstart = blockIdx.z * klen;
    float* __restrict__ Cpe = Cp + (size_t)blockIdx.z * M * N;

    const int lane = tid & 63;
    const int quad = lane >> 4;
    const int l16 = lane & 15;
    const int wave = tid >> 6;
    const int wm = (wave >> 1) * (BM / 2);
    const int wn = (wave & 1) * (BN / 2);

    int ar[IA], ac[IA];
    size_t abase[IA];
#pragma unroll
    for (int i = 0; i < IA; ++i) {
        const int g = tid + i * 256;
        ar[i] = g >> 2;
        ac[i] = (g & 3) * 8;
        if constexpr (CONV) {
            const int OW = 1 << lOW;
            const int m = m0 + ar[i];
            const int bidx = m >> (2 * lOW);
            const int pix = m & (OW * OW - 1);
            const int oy = pix >> lOW, ox = pix & (OW - 1);
            abase[i] = (size_t)(bidx * NTOK + (oy << ls) * 64 + (ox << ls)) << 9;
        } else {
            abase[i] = (size_t)(m0 + ar[i]) * K;
        }
    }
    int br[IB], bc[IB];
    size_t bbase[IB];
#pragma unroll
    for (int i = 0; i < IB; ++i) {
        const int g = tid + i * 256;
        br[i] = g >> 2;
        bc[i] = (g & 3) * 8;
        bbase[i] = (size_t)(n0 + br[i]) * K;
    }

    float4 axr[IA], ayr[IA], bxr[IB], byr[IB];
    auto load_t = [&](int t) {
        const int k = kstart + t * 32;
#pragma unroll
        for (int i = 0; i < IA; ++i) {
            size_t o;
            if constexpr (CONV) {
                const int p = k >> 9;
                const int ky = p >> ls, kx = p & ((1 << ls) - 1);
                o = abase[i] + ((size_t)(ky * 64 + kx) << 9) + (k & 511) + ac[i];
            } else {
                o = abase[i] + k + ac[i];
            }
            axr[i] = *(const float4*)(Ap + o);
            ayr[i] = *(const float4*)(Ap + o + 4);
        }
#pragma unroll
        for (int i = 0; i < IB; ++i) {
            const size_t o = bbase[i] + k + bc[i];
            bxr[i] = *(const float4*)(Bp + o);
            byr[i] = *(const float4*)(Bp + o + 4);
        }
    };

    f32x4 acc[FM][FN];
#pragma unroll
    for (int a = 0; a < FM; ++a)
#pragma unroll
        for (int b = 0; b < FN; ++b)
            acc[a][b] = (f32x4){0.f, 0.f, 0.f, 0.f};

    load_t(0);
    const int nk = klen >> 5;
    for (int t = 0; t < nk; ++t) {
        __syncthreads();
#pragma unroll
        for (int i = 0; i < IA; ++i)
            *(s16x8*)&As[ar[i]][ac[i]] = pack8(axr[i], ayr[i]);
#pragma unroll
        for (int i = 0; i < IB; ++i)
            *(s16x8*)&Bs[br[i]][bc[i]] = pack8(bxr[i], byr[i]);
        __syncthreads();
        if (t + 1 < nk) load_t(t + 1);

        s16x8 af[FM], bfv[FN];
#pragma unroll
        for (int f = 0; f < FM; ++f)
            af[f] = *(const s16x8*)&As[wm + f * 16 + l16][quad * 8];
#pragma unroll
        for (int f = 0; f < FN; ++f)
            bfv[f] = *(const s16x8*)&Bs[wn + f * 16 + l16][quad * 8];
#pragma unroll
        for (int a = 0; a < FM; ++a)
#pragma unroll
            for (int b = 0; b < FN; ++b)
                acc[a][b] = __builtin_amdgcn_mfma_f32_16x16x32_bf16(
                    af[a], bfv[b], acc[a][b], 0, 0, 0);
    }

#pragma unroll
    for (int a = 0; a < FM; ++a) {
        const int m = m0 + wm + a * 16 + quad * 4;
#pragma unroll
        for (int b = 0; b < FN; ++b) {
            const int n = n0 + wn + b * 16 + l16;
            const float bv = bias ? bias[n] : 0.f;
#pragma unroll
            for (int r = 0; r < 4; ++r)
                Cpe[(size_t)(m + r) * N + n] = acc[a][b][r] + bv;
        }
    }
}

// ---------------------------------------------------------------------------
// LayerNorm + ReLU6 with fused split-K reduction and conv bias.
// ---------------------------------------------------------------------------
__global__ __launch_bounds__(256) void ln_relu6_kernel(
    float* __restrict__ dst, const float* __restrict__ src, size_t pstride, int np,
    const float* __restrict__ cb, const float* __restrict__ g,
    const float* __restrict__ bta)
{
    const int row = blockIdx.x * 4 + (threadIdx.x >> 6);
    const int lane = threadIdx.x & 63;
    float v[8];
#pragma unroll
    for (int j = 0; j < 8; ++j) v[j] = cb[lane + 64 * j];
    const float* p = src + (size_t)row * DIM;
    for (int ip = 0; ip < np; ++ip) {
#pragma unroll
        for (int j = 0; j < 8; ++j) v[j] += p[lane + 64 * j];
        p += pstride;
    }
    float s1 = 0.f, s2 = 0.f;
#pragma unroll
    for (int j = 0; j < 8; ++j) { s1 += v[j]; s2 += v[j] * v[j]; }
#pragma unroll
    for (int off = 32; off; off >>= 1) {
        s1 += __shfl_xor(s1, off, 64);
        s2 += __shfl_xor(s2, off, 64);
    }
    const float mean = s1 * (1.0f / DIM);
    const float var = s2 * (1.0f / DIM) - mean * mean;
    const float rstd = rsqrtf(var + 1e-5f);
    float* q = dst + (size_t)row * DIM;
#pragma unroll
    for (int j = 0; j < 8; ++j) {
        const int c = lane + 64 * j;
        float y = (v[j] - mean) * rstd * g[c] + bta[c];
        q[c] = fminf(fmaxf(y, 0.0f), 6.0f);
    }
}

// ---------------------------------------------------------------------------
// vplus = v + dwconv3x3(v viewed as (B,C2,OW,OW)) + bias. One thread/element.
// ---------------------------------------------------------------------------
__global__ __launch_bounds__(256) void vplus_kernel(
    const float* __restrict__ vbuf, const float* __restrict__ lw,
    const float* __restrict__ lb, float* __restrict__ out, int lOW, int lL)
{
    const int idx = blockIdx.x * 256 + threadIdx.x;
    const int c = idx & 255;
    const int pix = (idx >> 8) & ((1 << lL) - 1);
    const int b = idx >> (8 + lL);
    const int OW = 1 << lOW;
    const int y = pix >> lOW, x = pix & (OW - 1);
    float acc = lb[c];
#pragma unroll
    for (int dy = -1; dy <= 1; ++dy) {
        const int ny = y + dy;
        if ((unsigned)ny >= (unsigned)OW) continue;
#pragma unroll
        for (int dx = -1; dx <= 1; ++dx) {
            const int nx = x + dx;
            if ((unsigned)nx >= (unsigned)OW) continue;
            acc += vbuf[(((size_t)(b << lL) + ny * OW + nx) << 8) + c] *
                   lw[c * 9 + (dy + 1) * 3 + (dx + 1)];
        }
    }
    out[idx] = vbuf[idx] + acc;
}

// ---------------------------------------------------------------------------
// MFMA attention. One block = 16-query tile for one (b,h).
// Phase A: S(16,L) = (Q*2^-3) K^T via 16x16x32 bf16 MFMA, S in LDS fp32.
// Phase B: full softmax per 4-rows-per-wave (exp unnormalized + invs[16]).
// Phase C: O = P V via MFMA (V staged transposed), scale by invs in epilogue.
// Fragment layouts as verified in mfma_gemm (round-1 pass).
// ---------------------------------------------------------------------------
template <int L>
__global__ __launch_bounds__(256) void attn_mfma(
    const float* __restrict__ qbuf, const float* __restrict__ kbuf,
    const float* __restrict__ vbuf, float* __restrict__ xbuf,
    int hoff, int coff)
{
    constexpr int SP = L + 12;         // fp32 row pad: 16B-aligned rows, 2-way banks
    constexpr int NV = L / 64;
    __shared__ float S[16][SP];
    __shared__ float invs[16];
    __shared__ alignas(16) short Qs[16][72];
    __shared__ alignas(16) short KV[64][72];   // K-tile rows l; then Vt rows d

    const int tid = threadIdx.x;
    const int qt = blockIdx.x;   // 0..12
    const int h = blockIdx.y;    // 0..3
    const int b = blockIdx.z;    // 0..7
    const int lane = tid & 63, wave = tid >> 6;
    const int l16 = lane & 15, quad = lane >> 4;

    // ---- load Q tile (scaled by 2^-3, exact in bf16) ----
    {
        const int r = tid >> 4, d0 = (tid & 15) * 4;
        int qi = qt * 16 + r; if (qi > QN - 1) qi = QN - 1;
        const float4 v = *(const float4*)(
            qbuf + ((size_t)(b * QN + qi) * NHEAD + hoff + h) * HD + d0);
        s16x4 o;
        o[0] = (short)f2bf(v.x * 0.125f); o[1] = (short)f2bf(v.y * 0.125f);
        o[2] = (short)f2bf(v.z * 0.125f); o[3] = (short)f2bf(v.w * 0.125f);
        *(s16x4*)&Qs[r][d0] = o;
    }

    // ---- Phase A: S = Q K^T ----
    const int klr = tid >> 2, kd0 = (tid & 3) * 16;
    for (int l0 = 0; l0 < L; l0 += 64) {
        const float* src = kbuf + ((size_t)(b * L) + l0 + klr) * C2 + h * HD + kd0;
        const float4 x0 = *(const float4*)(src);
        const float4 x1 = *(const float4*)(src + 4);
        const float4 x2 = *(const float4*)(src + 8);
        const float4 x3 = *(const float4*)(src + 12);
        __syncthreads();   // previous tile's MFMA reads done
        *(s16x8*)&KV[klr][kd0]     = pack8(x0, x1);
        *(s16x8*)&KV[klr][kd0 + 8] = pack8(x2, x3);
        __syncthreads();
        f32x4 sacc = (f32x4){0.f, 0.f, 0.f, 0.f};
#pragma unroll
        for (int c = 0; c < 2; ++c) {
            const s16x8 af = *(const s16x8*)&Qs[l16][c * 32 + quad * 8];
            const s16x8 bf = *(const s16x8*)&KV[wave * 16 + l16][c * 32 + quad * 8];
            sacc = __builtin_amdgcn_mfma_f32_16x16x32_bf16(af, bf, sacc, 0, 0, 0);
        }
        const int col = l0 + wave * 16 + l16;
#pragma unroll
        for (int r = 0; r < 4; ++r) S[quad * 4 + r][col] = sacc[r];
    }
    __syncthreads();

    // ---- Phase B: softmax (4 rows per wave, full row per wave) ----
#pragma unroll
    for (int rr = 0; rr < 4; ++rr) {
        const int row = wave * 4 + rr;
        float v[NV];
#pragma unroll
        for (int k = 0; k < NV; ++k) v[k] = S[row][lane + 64 * k];
        float m = -1e30f;
#pragma unroll
        for (int k = 0; k < NV; ++k) m = fmaxf(m, v[k]);
#pragma unroll
        for (int off = 32; off; off >>= 1) m = fmaxf(m, __shfl_xor(m, off, 64));
        float s = 0.f;
#pragma unroll
        for (int k = 0; k < NV; ++k) {
            v[k] = __expf(v[k] - m);
            s += v[k];
        }
#pragma unroll
        for (int off = 32; off; off >>= 1) s += __shfl_xor(s, off, 64);
#pragma unroll
        for (int k = 0; k < NV; ++k) S[row][lane + 64 * k] = v[k];
        if (lane == 0) invs[row] = 1.0f / s;
    }

    // ---- Phase C: O = P V ----
    f32x4 oacc = (f32x4){0.f, 0.f, 0.f, 0.f};
    const int vl = tid >> 4, vd0 = (tid & 15) * 4;
    for (int l0 = 0; l0 < L; l0 += 64) {
        float4 vr[4];
#pragma unroll
        for (int p = 0; p < 4; ++p)
            vr[p] = *(const float4*)(
                vbuf + ((size_t)(b * L) + l0 + p * 16 + vl) * C2 + h * HD + vd0);
        __syncthreads();   // previous tile's MFMA reads done (also covers softmax)
#pragma unroll
        for (int p = 0; p < 4; ++p) {
            const int ll = p * 16 + vl;
            KV[vd0 + 0][ll] = (short)f2bf(vr[p].x);
            KV[vd0 + 1][ll] = (short)f2bf(vr[p].y);
            KV[vd0 + 2][ll] = (short)f2bf(vr[p].z);
            KV[vd0 + 3][ll] = (short)f2bf(vr[p].w);
        }
        __syncthreads();
#pragma unroll
        for (int c = 0; c < 2; ++c) {
            const float4 p0 = *(const float4*)&S[l16][l0 + c * 32 + quad * 8];
            const float4 p1 = *(const float4*)&S[l16][l0 + c * 32 + quad * 8 + 4];
            const s16x8 af = pack8(p0, p1);
            const s16x8 bf = *(const s16x8*)&KV[wave * 16 + l16][c * 32 + quad * 8];
            oacc = __builtin_amdgcn_mfma_f32_16x16x32_bf16(af, bf, oacc, 0, 0, 0);
        }
    }

    // ---- epilogue ----
    const int dcol = wave * 16 + l16;
#pragma unroll
    for (int r = 0; r < 4; ++r) {
        const int q = quad * 4 + r;
        const int qi = qt * 16 + q;
        if (qi < QN) {
            const float val = oacc[r] * invs[q];
            const int flat = ((b * QN + qi) * NH2 + h) * HD + dcol;
            xbuf[(size_t)(flat >> 8) * DIM + coff + (flat & 255)] = val;
        }
    }
}

// ---------------------------------------------------------------------------
// Launcher
// ---------------------------------------------------------------------------
extern "C" void kernel_launch(void* const* d_in, const int* in_sizes, int n_in,
                              void* d_out, int out_size, void* d_ws, size_t ws_size,
                              hipStream_t stream)
{
    const float* query   = (const float*)d_in[0];
    const float* key     = (const float*)d_in[1];
    const float* value   = (const float*)d_in[2];
    const float* q_w     = (const float*)d_in[3];
    const float* sr1_1_w = (const float*)d_in[4];
    const float* sr1_1_b = (const float*)d_in[5];
    const float* n1_1_g  = (const float*)d_in[6];
    const float* n1_1_b  = (const float*)d_in[7];
    const float* sr1_2_w = (const float*)d_in[8];
    const float* sr1_2_b = (const float*)d_in[9];
    const float* n1_2_g  = (const float*)d_in[10];
    const float* n1_2_b  = (const float*)d_in[11];
    const float* sr2_1_w = (const float*)d_in[12];
    const float* sr2_1_b = (const float*)d_in[13];
    const float* n2_1_g  = (const float*)d_in[14];
    const float* n2_1_b  = (const float*)d_in[15];
    const float* sr2_2_w = (const float*)d_in[16];
    const float* sr2_2_b = (const float*)d_in[17];
    const float* n2_2_g  = (const float*)d_in[18];
    const float* n2_2_b  = (const float*)d_in[19];
    const float* k1_w    = (const float*)d_in[20];
    const float* v1_w    = (const float*)d_in[21];
    const float* k2_w    = (const float*)d_in[22];
    const float* v2_w    = (const float*)d_in[23];
    const float* lc1_w   = (const float*)d_in[24];
    const float* lc1_b   = (const float*)d_in[25];
    const float* lc2_w   = (const float*)d_in[26];
    const float* lc2_b   = (const float*)d_in[27];
    const float* proj_w  = (const float*)d_in[28];
    const float* proj_b  = (const float*)d_in[29];
    float* out = (float*)d_out;
    float* wsf = (float*)d_ws;

    // --- workspace (float offsets); total 20,971,520 floats = 80 MB ---
    float* WT1K = wsf + 0;
    float* WT1V = wsf + 4194304;
    float* WT2K = wsf + 8388608;
    float* WT2V = wsf + 9437184;
    float* KEY1 = wsf + 10485760;
    float* VAL1 = wsf + 11534336;
    float* KEY2 = wsf + 12582912;
    float* VAL2 = wsf + 16777216;
    float* K1   = wsf + 0;
    float* V1   = wsf + 524288;
    float* VP1  = wsf + 1048576;
    float* QBUF = wsf + 1572864;
    float* XBUF = wsf + 2392064;
    float* K2   = wsf + 4194304;
    float* V2   = wsf + 6291456;
    float* VP2  = wsf + 8388608;
    float* SCRK = KEY2;
    float* SCRV = VAL2;

    // 1) conv weight transposes (fp32)
    wtrans_kernel<<<512, 256, 0, stream>>>(sr1_1_w, WT1K, 16, 4);
    wtrans_kernel<<<512, 256, 0, stream>>>(sr1_2_w, WT1V, 16, 4);
    wtrans_kernel<<<512, 256, 0, stream>>>(sr2_1_w, WT2K, 4, 2);
    wtrans_kernel<<<512, 256, 0, stream>>>(sr2_2_w, WT2V, 4, 2);

    // 2) conv GEMMs (MFMA bf16) + fused-reduction LN
    mfma_gemm<128, 128, 1><<<dim3(4, 16, 4), 256, 0, stream>>>(
        key, WT1K, nullptr, SCRK, 2048, 512, 8192, 2048, 4, 2);
    ln_relu6_kernel<<<512, 256, 0, stream>>>(KEY1, SCRK, 1048576, 4, sr1_1_b, n1_1_g, n1_1_b);
    mfma_gemm<128, 128, 1><<<dim3(4, 64, 1), 256, 0, stream>>>(
        key, WT2K, nullptr, KEY2, 8192, 512, 2048, 2048, 5, 1);
    ln_relu6_kernel<<<2048, 256, 0, stream>>>(KEY2, KEY2, 0, 1, sr2_1_b, n2_1_g, n2_1_b);
    mfma_gemm<128, 128, 1><<<dim3(4, 16, 4), 256, 0, stream>>>(
        value, WT1V, nullptr, SCRV, 2048, 512, 8192, 2048, 4, 2);
    ln_relu6_kernel<<<512, 256, 0, stream>>>(VAL1, SCRV, 1048576, 4, sr1_2_b, n1_2_g, n1_2_b);
    mfma_gemm<128, 128, 1><<<dim3(4, 64, 1), 256, 0, stream>>>(
        value, WT2V, nullptr, VAL2, 8192, 512, 2048, 2048, 5, 1);
    ln_relu6_kernel<<<2048, 256, 0, stream>>>(VAL2, VAL2, 0, 1, sr2_2_b, n2_2_g, n2_2_b);

    // 3) q projection
    mfma_gemm<64, 64, 0><<<dim3(8, 25, 1), 256, 0, stream>>>(
        query, q_w, nullptr, QBUF, 1600, 512, 512, 512, 0, 0);

    // 4) k/v head projections
    mfma_gemm<64, 64, 0><<<dim3(4, 32, 1), 256, 0, stream>>>(
        KEY1, k1_w, nullptr, K1, 2048, 256, 512, 512, 0, 0);
    mfma_gemm<64, 64, 0><<<dim3(4, 32, 1), 256, 0, stream>>>(
        VAL1, v1_w, nullptr, V1, 2048, 256, 512, 512, 0, 0);
    mfma_gemm<64, 64, 0><<<dim3(4, 128, 1), 256, 0, stream>>>(
        KEY2, k2_w, nullptr, K2, 8192, 256, 512, 512, 0, 0);
    mfma_gemm<64, 64, 0><<<dim3(4, 128, 1), 256, 0, stream>>>(
        VAL2, v2_w, nullptr, V2, 8192, 256, 512, 512, 0, 0);

    // 5) v + local dwconv
    vplus_kernel<<<2048, 256, 0, stream>>>(V1, lc1_w, lc1_b, VP1, 4, 8);
    vplus_kernel<<<8192, 256, 0, stream>>>(V2, lc2_w, lc2_b, VP2, 5, 10);

    // 6) attention (MFMA)
    attn_mfma<256><<<dim3(13, 4, 8), 256, 0, stream>>>(QBUF, K1, VP1, XBUF, 0, 0);
    attn_mfma<1024><<<dim3(13, 4, 8), 256, 0, stream>>>(QBUF, K2, VP2, XBUF, 4, 256);

    // 7) final projection + bias
    mfma_gemm<64, 64, 0><<<dim3(8, 25, 1), 256, 0, stream>>>(
        XBUF, proj_w, proj_b, out, 1600, 512, 512, 512, 0, 0);
}

// Round 4
// 673.722 us; speedup vs baseline: 2.8933x; 1.0566x over previous
//
#include <hip/hip_runtime.h>
#include <cstddef>

// Problem constants
#define QN   200
#define DIM  512
#define NHEAD 8
#define HD   64
#define C2   256
#define NH2  4
#define NTOK 4096   // 64*64

typedef unsigned short ushort_t;
typedef short s16x4 __attribute__((ext_vector_type(4)));
typedef short s16x8 __attribute__((ext_vector_type(8)));   // 8 bf16 (4 VGPRs)
typedef float f32x4 __attribute__((ext_vector_type(4)));   // MFMA accumulator

__device__ __forceinline__ unsigned short f2bf(float f) {
    unsigned int u = __float_as_uint(f);
    u += 0x7fffu + ((u >> 16) & 1u);   // round-to-nearest-even
    return (unsigned short)(u >> 16);
}
__device__ __forceinline__ float bf2f(unsigned short u) {
    return __uint_as_float(((unsigned int)u) << 16);
}

__device__ __forceinline__ s16x8 pack8(float4 x, float4 y) {
    s16x8 v;
    v[0] = (short)f2bf(x.x); v[1] = (short)f2bf(x.y);
    v[2] = (short)f2bf(x.z); v[3] = (short)f2bf(x.w);
    v[4] = (short)f2bf(y.x); v[5] = (short)f2bf(y.y);
    v[6] = (short)f2bf(y.z); v[7] = (short)f2bf(y.w);
    return v;
}

// ---------------------------------------------------------------------------
// fp32 -> bf16 elementwise (n8 = n/8 groups)
// ---------------------------------------------------------------------------
__global__ __launch_bounds__(256) void cvt_f2b(
    const float* __restrict__ src, ushort_t* __restrict__ dst, int n8)
{
    const int i = blockIdx.x * 256 + threadIdx.x;
    if (i >= n8) return;
    const float4 a = ((const float4*)src)[i * 2];
    const float4 b = ((const float4*)src)[i * 2 + 1];
    ((s16x8*)dst)[i] = pack8(a, b);
}

// ---------------------------------------------------------------------------
// Weight transpose: w (512, 512, KK) fp32 -> wt (512, KK*512) bf16, k'=p*512+ci
// ---------------------------------------------------------------------------
__global__ __launch_bounds__(256) void wtrans_kernel(
    const float* __restrict__ w, ushort_t* __restrict__ wt, int KK, int lKK)
{
    __shared__ float tile[512 * 17];
    const int c = blockIdx.x;
    const int K = KK << 9;
    const float* src = w + (size_t)c * K;
    ushort_t* dst = wt + (size_t)c * K;
    for (int i = threadIdx.x; i < K; i += 256) {
        int ci = i >> lKK, p = i & (KK - 1);
        tile[ci * (KK + 1) + p] = src[i];
    }
    __syncthreads();
    for (int i = threadIdx.x; i < K; i += 256) {
        int p = i >> 9, ci = i & 511;
        dst[i] = f2bf(tile[ci * (KK + 1) + p]);
    }
}

// ---------------------------------------------------------------------------
// MFMA bf16 GEMM: C(M,N) = A(M,K) * B(N,K)^T, B bf16 row-major.
// MODE 0: A bf16 row-major.  MODE 1: A fp32 conv-patch gather (pack in reg).
// OBF 0: C fp32 (+bias, +z*M*N partial offset). OBF 1: C bf16 (scale, bias).
// Double-buffered LDS, XOR-swizzled (16B blocks), 1 barrier/iter, BK=32.
// 256 threads = 2x2 waves; wave tile (BM/2)x(BN/2).
// ---------------------------------------------------------------------------
template <int BM, int BN, int MODE, int OBF>
__global__ __launch_bounds__(256) void mfma_gemm(
    const void* __restrict__ Ap_, const ushort_t* __restrict__ Bp,
    const float* __restrict__ bias, void* __restrict__ Cp_,
    int M, int N, int K, int klen, int lOW, int ls, float oscale)
{
    constexpr int ASZ = BM * 32;
    constexpr int BSZ = BN * 32;
    constexpr int IA = BM / 64;
    constexpr int IB = BN / 64;
    constexpr int FM = BM / 32;
    constexpr int FN = BN / 32;
    __shared__ short lds[2 * (ASZ + BSZ)];

    const int tid = threadIdx.x;
    const int m0 = blockIdx.y * BM;
    const int n0 = blockIdx.x * BN;
    const int kstart = blockIdx.z * klen;
    const int lane = tid & 63, wave = tid >> 6;
    const int l16 = lane & 15, quad = lane >> 4;
    const int wm = (wave >> 1) * (BM / 2);
    const int wn = (wave & 1) * (BN / 2);

    const float* __restrict__ Af = (const float*)Ap_;
    const ushort_t* __restrict__ Ab = (const ushort_t*)Ap_;

    // swizzled LDS short-offset for (row r, 8-short block c in 0..3)
    auto off = [](int r, int c) -> int {
        return ((r >> 1) << 6) + (((((r & 1) << 2) | c) ^ ((r >> 1) & 7)) << 3);
    };

    // staging maps
    unsigned abase[IA]; int acs[IA], offA[IA];
#pragma unroll
    for (int i = 0; i < IA; ++i) {
        const int g = tid + i * 256;
        const int r = g >> 2;
        acs[i] = (g & 3) * 8;
        offA[i] = off(r, g & 3);
        if constexpr (MODE == 1) {
            const int OW = 1 << lOW;
            const int m = m0 + r;
            const int bidx = m >> (2 * lOW);
            const int pix = m & (OW * OW - 1);
            const int oy = pix >> lOW, ox = pix & (OW - 1);
            abase[i] = (unsigned)(bidx * NTOK + (oy << ls) * 64 + (ox << ls)) << 9;
        } else {
            abase[i] = (unsigned)(m0 + r) * K;
        }
    }
    unsigned bbase[IB]; int bcs[IB], offB[IB];
#pragma unroll
    for (int i = 0; i < IB; ++i) {
        const int g = tid + i * 256;
        bcs[i] = (g & 3) * 8;
        offB[i] = off(g >> 2, g & 3);
        bbase[i] = (unsigned)(n0 + (g >> 2)) * K;
    }

    s16x8 aR[IA], bR[IB];
    auto loadg = [&](int t) {
        const int k = kstart + t * 32;
#pragma unroll
        for (int i = 0; i < IA; ++i) {
            if constexpr (MODE == 1) {
                const int p = k >> 9;
                const int ky = p >> ls, kx = p & ((1 << ls) - 1);
                const unsigned o = abase[i] + ((unsigned)(ky * 64 + kx) << 9) +
                                   (k & 511) + acs[i];
                const float4 x = *(const float4*)(Af + o);
                const float4 y = *(const float4*)(Af + o + 4);
                aR[i] = pack8(x, y);
            } else {
                aR[i] = *(const s16x8*)(Ab + abase[i] + k + acs[i]);
            }
        }
#pragma unroll
        for (int i = 0; i < IB; ++i)
            bR[i] = *(const s16x8*)(Bp + bbase[i] + k + bcs[i]);
    };
    auto stg = [&](int buf) {
        short* A = lds + buf * (ASZ + BSZ);
        short* Bs = A + ASZ;
#pragma unroll
        for (int i = 0; i < IA; ++i) *(s16x8*)&A[offA[i]] = aR[i];
#pragma unroll
        for (int i = 0; i < IB; ++i) *(s16x8*)&Bs[offB[i]] = bR[i];
    };

    f32x4 acc[FM][FN];
#pragma unroll
    for (int a = 0; a < FM; ++a)
#pragma unroll
        for (int b = 0; b < FN; ++b)
            acc[a][b] = (f32x4){0.f, 0.f, 0.f, 0.f};

    loadg(0);
    stg(0);
    __syncthreads();
    const int nk = klen >> 5;
    for (int t = 0; t < nk; ++t) {
        if (t + 1 < nk) loadg(t + 1);
        const short* A = lds + (t & 1) * (ASZ + BSZ);
        const short* Bs = A + ASZ;
        s16x8 af[FM], bfv[FN];
#pragma unroll
        for (int f = 0; f < FM; ++f)
            af[f] = *(const s16x8*)&A[off(wm + f * 16 + l16, quad)];
#pragma unroll
        for (int f = 0; f < FN; ++f)
            bfv[f] = *(const s16x8*)&Bs[off(wn + f * 16 + l16, quad)];
#pragma unroll
        for (int a = 0; a < FM; ++a)
#pragma unroll
            for (int b = 0; b < FN; ++b)
                acc[a][b] = __builtin_amdgcn_mfma_f32_16x16x32_bf16(
                    af[a], bfv[b], acc[a][b], 0, 0, 0);
        if (t + 1 < nk) {
            stg((t + 1) & 1);
            __syncthreads();
        }
    }

    // epilogue: C/D layout col=lane&15, row=quad*4+reg
    const unsigned zoff = (unsigned)blockIdx.z * (unsigned)(M) * (unsigned)N;
#pragma unroll
    for (int a = 0; a < FM; ++a) {
        const int m = m0 + wm + a * 16 + quad * 4;
#pragma unroll
        for (int b = 0; b < FN; ++b) {
            const int n = n0 + wn + b * 16 + l16;
            const float bv = bias ? bias[n] : 0.f;
#pragma unroll
            for (int r = 0; r < 4; ++r) {
                const float val = acc[a][b][r] * oscale + bv;
                if constexpr (OBF)
                    ((ushort_t*)Cp_)[(unsigned)(m + r) * N + n] = f2bf(val);
                else
                    ((float*)Cp_)[zoff + (unsigned)(m + r) * N + n] = val;
            }
        }
    }
}

// ---------------------------------------------------------------------------
// LayerNorm + ReLU6 with fused split-K reduction + conv bias. dst bf16.
// ---------------------------------------------------------------------------
__global__ __launch_bounds__(256) void ln_relu6_kernel(
    ushort_t* __restrict__ dst, const float* __restrict__ src, unsigned pstride,
    int np, const float* __restrict__ cb, const float* __restrict__ g,
    const float* __restrict__ bta)
{
    const int row = blockIdx.x * 4 + (threadIdx.x >> 6);
    const int lane = threadIdx.x & 63;
    float v[8];
#pragma unroll
    for (int j = 0; j < 8; ++j) v[j] = cb[lane + 64 * j];
    const float* p = src + (size_t)row * DIM;
    for (int ip = 0; ip < np; ++ip) {
#pragma unroll
        for (int j = 0; j < 8; ++j) v[j] += p[lane + 64 * j];
        p += pstride;
    }
    float s1 = 0.f, s2 = 0.f;
#pragma unroll
    for (int j = 0; j < 8; ++j) { s1 += v[j]; s2 += v[j] * v[j]; }
#pragma unroll
    for (int off = 32; off; off >>= 1) {
        s1 += __shfl_xor(s1, off, 64);
        s2 += __shfl_xor(s2, off, 64);
    }
    const float mean = s1 * (1.0f / DIM);
    const float var = s2 * (1.0f / DIM) - mean * mean;
    const float rstd = rsqrtf(var + 1e-5f);
    ushort_t* q = dst + (size_t)row * DIM;
#pragma unroll
    for (int j = 0; j < 8; ++j) {
        const int c = lane + 64 * j;
        float y = (v[j] - mean) * rstd * g[c] + bta[c];
        q[c] = f2bf(fminf(fmaxf(y, 0.0f), 6.0f));
    }
}

// ---------------------------------------------------------------------------
// vplus = v + dwconv3x3(v viewed as (B,C2,OW,OW)) + bias. bf16 in/out.
// ---------------------------------------------------------------------------
__global__ __launch_bounds__(256) void vplus_kernel(
    const ushort_t* __restrict__ vbuf, const float* __restrict__ lw,
    const float* __restrict__ lb, ushort_t* __restrict__ out, int lOW, int lL)
{
    const int idx = blockIdx.x * 256 + threadIdx.x;
    const int c = idx & 255;
    const int pix = (idx >> 8) & ((1 << lL) - 1);
    const int b = idx >> (8 + lL);
    const int OW = 1 << lOW;
    const int y = pix >> lOW, x = pix & (OW - 1);
    float acc = lb[c];
#pragma unroll
    for (int dy = -1; dy <= 1; ++dy) {
        const int ny = y + dy;
        if ((unsigned)ny >= (unsigned)OW) continue;
#pragma unroll
        for (int dx = -1; dx <= 1; ++dx) {
            const int nx = x + dx;
            if ((unsigned)nx >= (unsigned)OW) continue;
            acc += bf2f(vbuf[(((unsigned)(b << lL) + ny * OW + nx) << 8) + c]) *
                   lw[c * 9 + (dy + 1) * 3 + (dx + 1)];
        }
    }
    out[idx] = f2bf(bf2f(vbuf[idx]) + acc);
}

// ---------------------------------------------------------------------------
// MFMA attention, all operands bf16 (Q pre-scaled by 0.125 in q-projection).
// ---------------------------------------------------------------------------
template <int L>
__global__ __launch_bounds__(256) void attn_mfma(
    const ushort_t* __restrict__ qbuf, const ushort_t* __restrict__ kbuf,
    const ushort_t* __restrict__ vbuf, ushort_t* __restrict__ xbuf,
    int hoff, int coff)
{
    constexpr int SP = L + 12;
    constexpr int NV = L / 64;
    __shared__ float S[16][SP];
    __shared__ float invs[16];
    __shared__ alignas(16) short Qs[16][72];
    __shared__ alignas(16) short KV[64][72];

    const int tid = threadIdx.x;
    const int qt = blockIdx.x;
    const int h = blockIdx.y;
    const int b = blockIdx.z;
    const int lane = tid & 63, wave = tid >> 6;
    const int l16 = lane & 15, quad = lane >> 4;

    // ---- load Q tile (bf16, already scaled) ----
    {
        const int r = tid >> 4, d0 = (tid & 15) * 4;
        int qi = qt * 16 + r; if (qi > QN - 1) qi = QN - 1;
        *(s16x4*)&Qs[r][d0] = *(const s16x4*)(
            qbuf + ((unsigned)(b * QN + qi) * NHEAD + hoff + h) * HD + d0);
    }

    // ---- Phase A: S = Q K^T ----
    const int klr = tid >> 2, kd0 = (tid & 3) * 16;
    for (int l0 = 0; l0 < L; l0 += 64) {
        const unsigned src = (unsigned)(b * L + l0 + klr) * C2 + h * HD + kd0;
        const s16x8 x0 = *(const s16x8*)(kbuf + src);
        const s16x8 x1 = *(const s16x8*)(kbuf + src + 8);
        __syncthreads();
        *(s16x8*)&KV[klr][kd0] = x0;
        *(s16x8*)&KV[klr][kd0 + 8] = x1;
        __syncthreads();
        f32x4 sacc = (f32x4){0.f, 0.f, 0.f, 0.f};
#pragma unroll
        for (int c = 0; c < 2; ++c) {
            const s16x8 af = *(const s16x8*)&Qs[l16][c * 32 + quad * 8];
            const s16x8 bf = *(const s16x8*)&KV[wave * 16 + l16][c * 32 + quad * 8];
            sacc = __builtin_amdgcn_mfma_f32_16x16x32_bf16(af, bf, sacc, 0, 0, 0);
        }
        const int col = l0 + wave * 16 + l16;
#pragma unroll
        for (int r = 0; r < 4; ++r) S[quad * 4 + r][col] = sacc[r];
    }
    __syncthreads();

    // ---- Phase B: softmax (4 rows per wave) ----
#pragma unroll
    for (int rr = 0; rr < 4; ++rr) {
        const int row = wave * 4 + rr;
        float v[NV];
#pragma unroll
        for (int k = 0; k < NV; ++k) v[k] = S[row][lane + 64 * k];
        float m = -1e30f;
#pragma unroll
        for (int k = 0; k < NV; ++k) m = fmaxf(m, v[k]);
#pragma unroll
        for (int off = 32; off; off >>= 1) m = fmaxf(m, __shfl_xor(m, off, 64));
        float s = 0.f;
#pragma unroll
        for (int k = 0; k < NV; ++k) {
            v[k] = __expf(v[k] - m);
            s += v[k];
        }
#pragma unroll
        for (int off = 32; off; off >>= 1) s += __shfl_xor(s, off, 64);
#pragma unroll
        for (int k = 0; k < NV; ++k) S[row][lane + 64 * k] = v[k];
        if (lane == 0) invs[row] = 1.0f / s;
    }

    // ---- Phase C: O = P V ----
    f32x4 oacc = (f32x4){0.f, 0.f, 0.f, 0.f};
    const int vl = tid >> 4, vd0 = (tid & 15) * 4;
    for (int l0 = 0; l0 < L; l0 += 64) {
        s16x4 vr[4];
#pragma unroll
        for (int p = 0; p < 4; ++p)
            vr[p] = *(const s16x4*)(
                vbuf + (unsigned)(b * L + l0 + p * 16 + vl) * C2 + h * HD + vd0);
        __syncthreads();
#pragma unroll
        for (int p = 0; p < 4; ++p) {
            const int ll = p * 16 + vl;
            KV[vd0 + 0][ll] = vr[p][0];
            KV[vd0 + 1][ll] = vr[p][1];
            KV[vd0 + 2][ll] = vr[p][2];
            KV[vd0 + 3][ll] = vr[p][3];
        }
        __syncthreads();
#pragma unroll
        for (int c = 0; c < 2; ++c) {
            const float4 p0 = *(const float4*)&S[l16][l0 + c * 32 + quad * 8];
            const float4 p1 = *(const float4*)&S[l16][l0 + c * 32 + quad * 8 + 4];
            const s16x8 af = pack8(p0, p1);
            const s16x8 bf = *(const s16x8*)&KV[wave * 16 + l16][c * 32 + quad * 8];
            oacc = __builtin_amdgcn_mfma_f32_16x16x32_bf16(af, bf, oacc, 0, 0, 0);
        }
    }

    // ---- epilogue ----
    const int dcol = wave * 16 + l16;
#pragma unroll
    for (int r = 0; r < 4; ++r) {
        const int q = quad * 4 + r;
        const int qi = qt * 16 + q;
        if (qi < QN) {
            const float val = oacc[r] * invs[q];
            const int flat = ((b * QN + qi) * NH2 + h) * HD + dcol;
            xbuf[(unsigned)(flat >> 8) * DIM + coff + (flat & 255)] = f2bf(val);
        }
    }
}

// ---------------------------------------------------------------------------
// Launcher
// ---------------------------------------------------------------------------
extern "C" void kernel_launch(void* const* d_in, const int* in_sizes, int n_in,
                              void* d_out, int out_size, void* d_ws, size_t ws_size,
                              hipStream_t stream)
{
    const float* query   = (const float*)d_in[0];
    const float* key     = (const float*)d_in[1];
    const float* value   = (const float*)d_in[2];
    const float* q_w     = (const float*)d_in[3];
    const float* sr1_1_w = (const float*)d_in[4];
    const float* sr1_1_b = (const float*)d_in[5];
    const float* n1_1_g  = (const float*)d_in[6];
    const float* n1_1_b  = (const float*)d_in[7];
    const float* sr1_2_w = (const float*)d_in[8];
    const float* sr1_2_b = (const float*)d_in[9];
    const float* n1_2_g  = (const float*)d_in[10];
    const float* n1_2_b  = (const float*)d_in[11];
    const float* sr2_1_w = (const float*)d_in[12];
    const float* sr2_1_b = (const float*)d_in[13];
    const float* n2_1_g  = (const float*)d_in[14];
    const float* n2_1_b  = (const float*)d_in[15];
    const float* sr2_2_w = (const float*)d_in[16];
    const float* sr2_2_b = (const float*)d_in[17];
    const float* n2_2_g  = (const float*)d_in[18];
    const float* n2_2_b  = (const float*)d_in[19];
    const float* k1_w    = (const float*)d_in[20];
    const float* v1_w    = (const float*)d_in[21];
    const float* k2_w    = (const float*)d_in[22];
    const float* v2_w    = (const float*)d_in[23];
    const float* lc1_w   = (const float*)d_in[24];
    const float* lc1_b   = (const float*)d_in[25];
    const float* lc2_w   = (const float*)d_in[26];
    const float* lc2_b   = (const float*)d_in[27];
    const float* proj_w  = (const float*)d_in[28];
    const float* proj_b  = (const float*)d_in[29];
    float* out = (float*)d_out;
    char* ws = (char*)d_ws;

    // --- workspace layout (bytes); total 81,461,248 <= 80 MiB ---
    float*    SCR  = (float*)(ws + 0);            // 16.78 MB fp32, reused 4x
    ushort_t* WT1K = (ushort_t*)(ws + 16777216);  // 512x8192 bf16
    ushort_t* WT1V = (ushort_t*)(ws + 25165824);
    ushort_t* WT2K = (ushort_t*)(ws + 33554432);  // 512x2048 bf16
    ushort_t* WT2V = (ushort_t*)(ws + 35651584);
    ushort_t* KEY1 = (ushort_t*)(ws + 37748736);  // 2048x512 bf16
    ushort_t* VAL1 = (ushort_t*)(ws + 39845888);
    ushort_t* KEY2 = (ushort_t*)(ws + 41943040);  // 8192x512 bf16
    ushort_t* VAL2 = (ushort_t*)(ws + 50331648);
    ushort_t* QRYB = (ushort_t*)(ws + 58720256);  // 1600x512 bf16
    ushort_t* WQ   = (ushort_t*)(ws + 60358656);
    ushort_t* WK1  = (ushort_t*)(ws + 60882944);
    ushort_t* WV1  = (ushort_t*)(ws + 61145088);
    ushort_t* WK2  = (ushort_t*)(ws + 61407232);
    ushort_t* WV2  = (ushort_t*)(ws + 61669376);
    ushort_t* WP   = (ushort_t*)(ws + 61931520);
    ushort_t* QBUF = (ushort_t*)(ws + 62455808);  // 1600x512 bf16
    ushort_t* XBUF = (ushort_t*)(ws + 64094208);
    ushort_t* K1   = (ushort_t*)(ws + 65732608);  // 2048x256 bf16
    ushort_t* V1   = (ushort_t*)(ws + 66781184);
    ushort_t* VP1  = (ushort_t*)(ws + 67829760);
    ushort_t* K2   = (ushort_t*)(ws + 68878336);  // 8192x256 bf16
    ushort_t* V2   = (ushort_t*)(ws + 73072640);
    ushort_t* VP2  = (ushort_t*)(ws + 77266944);

    // 1) conversions + weight transposes
    cvt_f2b<<<400, 256, 0, stream>>>(query, QRYB, 102400);
    cvt_f2b<<<128, 256, 0, stream>>>(q_w, WQ, 32768);
    cvt_f2b<<<64, 256, 0, stream>>>(k1_w, WK1, 16384);
    cvt_f2b<<<64, 256, 0, stream>>>(v1_w, WV1, 16384);
    cvt_f2b<<<64, 256, 0, stream>>>(k2_w, WK2, 16384);
    cvt_f2b<<<64, 256, 0, stream>>>(v2_w, WV2, 16384);
    cvt_f2b<<<128, 256, 0, stream>>>(proj_w, WP, 32768);
    wtrans_kernel<<<512, 256, 0, stream>>>(sr1_1_w, WT1K, 16, 4);
    wtrans_kernel<<<512, 256, 0, stream>>>(sr1_2_w, WT1V, 16, 4);
    wtrans_kernel<<<512, 256, 0, stream>>>(sr2_1_w, WT2K, 4, 2);
    wtrans_kernel<<<512, 256, 0, stream>>>(sr2_2_w, WT2V, 4, 2);

    // 2) conv GEMMs (MFMA, A fp32-gather, B bf16) + fused-reduction LN -> bf16
    mfma_gemm<128, 64, 1, 0><<<dim3(8, 16, 4), 256, 0, stream>>>(
        key, WT1K, nullptr, SCR, 2048, 512, 8192, 2048, 4, 2, 1.0f);
    ln_relu6_kernel<<<512, 256, 0, stream>>>(KEY1, SCR, 1048576u, 4, sr1_1_b, n1_1_g, n1_1_b);
    mfma_gemm<128, 64, 1, 0><<<dim3(8, 16, 4), 256, 0, stream>>>(
        value, WT1V, nullptr, SCR, 2048, 512, 8192, 2048, 4, 2, 1.0f);
    ln_relu6_kernel<<<512, 256, 0, stream>>>(VAL1, SCR, 1048576u, 4, sr1_2_b, n1_2_g, n1_2_b);
    mfma_gemm<128, 64, 1, 0><<<dim3(8, 64, 1), 256, 0, stream>>>(
        key, WT2K, nullptr, SCR, 8192, 512, 2048, 2048, 5, 1, 1.0f);
    ln_relu6_kernel<<<2048, 256, 0, stream>>>(KEY2, SCR, 0u, 1, sr2_1_b, n2_1_g, n2_1_b);
    mfma_gemm<128, 64, 1, 0><<<dim3(8, 64, 1), 256, 0, stream>>>(
        value, WT2V, nullptr, SCR, 8192, 512, 2048, 2048, 5, 1, 1.0f);
    ln_relu6_kernel<<<2048, 256, 0, stream>>>(VAL2, SCR, 0u, 1, sr2_2_b, n2_2_g, n2_2_b);

    // 3) q projection (scale 0.125 folded in), bf16 out
    mfma_gemm<64, 64, 0, 1><<<dim3(8, 25, 1), 256, 0, stream>>>(
        QRYB, WQ, nullptr, QBUF, 1600, 512, 512, 512, 0, 0, 0.125f);

    // 4) k/v head projections, bf16 out
    mfma_gemm<64, 64, 0, 1><<<dim3(4, 32, 1), 256, 0, stream>>>(
        KEY1, WK1, nullptr, K1, 2048, 256, 512, 512, 0, 0, 1.0f);
    mfma_gemm<64, 64, 0, 1><<<dim3(4, 32, 1), 256, 0, stream>>>(
        VAL1, WV1, nullptr, V1, 2048, 256, 512, 512, 0, 0, 1.0f);
    mfma_gemm<64, 64, 0, 1><<<dim3(4, 128, 1), 256, 0, stream>>>(
        KEY2, WK2, nullptr, K2, 8192, 256, 512, 512, 0, 0, 1.0f);
    mfma_gemm<64, 64, 0, 1><<<dim3(4, 128, 1), 256, 0, stream>>>(
        VAL2, WV2, nullptr, V2, 8192, 256, 512, 512, 0, 0, 1.0f);

    // 5) v + local dwconv (bf16)
    vplus_kernel<<<2048, 256, 0, stream>>>(V1, lc1_w, lc1_b, VP1, 4, 8);
    vplus_kernel<<<8192, 256, 0, stream>>>(V2, lc2_w, lc2_b, VP2, 5, 10);

    // 6) attention (MFMA, bf16)
    attn_mfma<256><<<dim3(13, 4, 8), 256, 0, stream>>>(QBUF, K1, VP1, XBUF, 0, 0);
    attn_mfma<1024><<<dim3(13, 4, 8), 256, 0, stream>>>(QBUF, K2, VP2, XBUF, 4, 256);

    // 7) final projection + bias -> fp32 out
    mfma_gemm<64, 64, 0, 0><<<dim3(8, 25, 1), 256, 0, stream>>>(
        XBUF, WP, proj_b, out, 1600, 512, 512, 512, 0, 0, 1.0f);
}

// Round 5
// 543.981 us; speedup vs baseline: 3.5833x; 1.2385x over previous
//
#include <hip/hip_runtime.h>
#include <cstddef>

// Problem constants
#define QN   200
#define DIM  512
#define NHEAD 8
#define HD   64
#define C2   256
#define NH2  4
#define NTOK 4096   // 64*64

typedef unsigned short ushort_t;
typedef short s16x4 __attribute__((ext_vector_type(4)));
typedef short s16x8 __attribute__((ext_vector_type(8)));   // 8 bf16 (4 VGPRs)
typedef float f32x4 __attribute__((ext_vector_type(4)));   // MFMA accumulator

__device__ __forceinline__ unsigned short f2bf(float f) {
    unsigned int u = __float_as_uint(f);
    u += 0x7fffu + ((u >> 16) & 1u);   // round-to-nearest-even
    return (unsigned short)(u >> 16);
}
__device__ __forceinline__ float bf2f(unsigned short u) {
    return __uint_as_float(((unsigned int)u) << 16);
}

__device__ __forceinline__ s16x8 pack8(float4 x, float4 y) {
    s16x8 v;
    v[0] = (short)f2bf(x.x); v[1] = (short)f2bf(x.y);
    v[2] = (short)f2bf(x.z); v[3] = (short)f2bf(x.w);
    v[4] = (short)f2bf(y.x); v[5] = (short)f2bf(y.y);
    v[6] = (short)f2bf(y.z); v[7] = (short)f2bf(y.w);
    return v;
}

// ---------------------------------------------------------------------------
// fp32 -> bf16 elementwise (n8 = n/8 groups)
// ---------------------------------------------------------------------------
__global__ __launch_bounds__(256) void cvt_f2b(
    const float* __restrict__ src, ushort_t* __restrict__ dst, int n8)
{
    const int i = blockIdx.x * 256 + threadIdx.x;
    if (i >= n8) return;
    const float4 a = ((const float4*)src)[i * 2];
    const float4 b = ((const float4*)src)[i * 2 + 1];
    ((s16x8*)dst)[i] = pack8(a, b);
}

// ---------------------------------------------------------------------------
// Weight transpose: w (512, 512, KK) fp32 -> wt (512, KK*512) bf16, k'=p*512+ci
// ---------------------------------------------------------------------------
__global__ __launch_bounds__(256) void wtrans_kernel(
    const float* __restrict__ w, ushort_t* __restrict__ wt, int KK, int lKK)
{
    __shared__ float tile[512 * 17];
    const int c = blockIdx.x;
    const int K = KK << 9;
    const float* src = w + (size_t)c * K;
    ushort_t* dst = wt + (size_t)c * K;
    for (int i = threadIdx.x; i < K; i += 256) {
        int ci = i >> lKK, p = i & (KK - 1);
        tile[ci * (KK + 1) + p] = src[i];
    }
    __syncthreads();
    for (int i = threadIdx.x; i < K; i += 256) {
        int p = i >> 9, ci = i & 511;
        dst[i] = f2bf(tile[ci * (KK + 1) + p]);
    }
}

// ---------------------------------------------------------------------------
// Conv-patch GEMM (MFMA bf16): C(M,512) = gather(A fp32)(M,K) * B(512,K)^T
// BM=128, BN=64, BK=64. 1-D grid with XCD-aware swizzle:
//   xcd=bid&7, j=bid>>3, nt=j&7, mz=(j>>3)*8+xcd, mt=mz&(2^lMT-1), z=mz>>lMT
// so the 8 blocks sharing an A M-slice land on ONE XCD (L2 reuse).
// Writes fp32 partials at Cp + z*M*N (bias/reduction fused into LN).
// ---------------------------------------------------------------------------
__global__ __launch_bounds__(256) void conv_gemm(
    const float* __restrict__ Ap, const ushort_t* __restrict__ Bp,
    float* __restrict__ Cp, int M, int N, int K, int klen,
    int lOW, int ls, int lMT)
{
    constexpr int ASZ = 128 * 64;
    constexpr int BSZ = 64 * 64;
    __shared__ short lds[2 * (ASZ + BSZ)];

    const int tid = threadIdx.x;
    const int bid = blockIdx.x;
    const int xcd = bid & 7;
    const int j = bid >> 3;
    const int nt = j & 7;
    const int mz = (j >> 3) * 8 + xcd;
    const int mt = mz & ((1 << lMT) - 1);
    const int z = mz >> lMT;
    const int m0 = mt * 128, n0 = nt * 64;
    const int kstart = z * klen;

    const int lane = tid & 63, wave = tid >> 6;
    const int l16 = lane & 15, quad = lane >> 4;
    const int wm = (wave >> 1) * 64;
    const int wn = (wave & 1) * 32;

    // 64-short rows (128 B = 8 x 16B blocks): block c -> c ^ (r&7)
    auto off = [](int r, int c) -> int {
        return (r << 6) + ((c ^ (r & 7)) << 3);
    };

    // staging maps: A 128x64 (4 slots/thread), B 64x64 (2 slots)
    unsigned abase[4]; int offA[4], acx[4];
#pragma unroll
    for (int i = 0; i < 4; ++i) {
        const int g = tid + i * 256;
        const int r = g >> 3, c = g & 7;
        acx[i] = c * 8;
        offA[i] = off(r, c);
        const int OW = 1 << lOW;
        const int m = m0 + r;
        const int bidx = m >> (2 * lOW);
        const int pix = m & (OW * OW - 1);
        const int oy = pix >> lOW, ox = pix & (OW - 1);
        abase[i] = (unsigned)(bidx * NTOK + (oy << ls) * 64 + (ox << ls)) << 9;
    }
    unsigned bbase[2]; int offB[2], bcx[2];
#pragma unroll
    for (int i = 0; i < 2; ++i) {
        const int g = tid + i * 256;
        const int r = g >> 3, c = g & 7;
        bcx[i] = c * 8;
        offB[i] = off(r, c);
        bbase[i] = (unsigned)(n0 + r) * K;
    }

    float4 ax[4], ay[4];
    s16x8 bR[2];
    auto loadg = [&](int t) {
        const int k0 = kstart + t * 64;
#pragma unroll
        for (int i = 0; i < 4; ++i) {
            const int k = k0 + acx[i];
            const int p = k >> 9;
            const int ky = p >> ls, kx = p & ((1 << ls) - 1);
            const unsigned o = abase[i] + ((unsigned)(ky * 64 + kx) << 9) + (k & 511);
            ax[i] = *(const float4*)(Ap + o);
            ay[i] = *(const float4*)(Ap + o + 4);
        }
#pragma unroll
        for (int i = 0; i < 2; ++i)
            bR[i] = *(const s16x8*)(Bp + bbase[i] + k0 + bcx[i]);
    };
    auto stg = [&](int buf) {
        short* A = lds + buf * (ASZ + BSZ);
        short* Bs = A + ASZ;
#pragma unroll
        for (int i = 0; i < 4; ++i) *(s16x8*)&A[offA[i]] = pack8(ax[i], ay[i]);
#pragma unroll
        for (int i = 0; i < 2; ++i) *(s16x8*)&Bs[offB[i]] = bR[i];
    };

    f32x4 acc[4][2];
#pragma unroll
    for (int a = 0; a < 4; ++a)
#pragma unroll
        for (int b = 0; b < 2; ++b)
            acc[a][b] = (f32x4){0.f, 0.f, 0.f, 0.f};

    loadg(0);
    stg(0);
    __syncthreads();
    const int nk = klen >> 6;
    for (int t = 0; t < nk; ++t) {
        if (t + 1 < nk) loadg(t + 1);
        const short* A = lds + (t & 1) * (ASZ + BSZ);
        const short* Bs = A + ASZ;
#pragma unroll
        for (int kk = 0; kk < 2; ++kk) {
            s16x8 af[4], bf[2];
#pragma unroll
            for (int f = 0; f < 4; ++f)
                af[f] = *(const s16x8*)&A[off(wm + f * 16 + l16, quad + kk * 4)];
#pragma unroll
            for (int f = 0; f < 2; ++f)
                bf[f] = *(const s16x8*)&Bs[off(wn + f * 16 + l16, quad + kk * 4)];
#pragma unroll
            for (int a = 0; a < 4; ++a)
#pragma unroll
                for (int b = 0; b < 2; ++b)
                    acc[a][b] = __builtin_amdgcn_mfma_f32_16x16x32_bf16(
                        af[a], bf[b], acc[a][b], 0, 0, 0);
        }
        if (t + 1 < nk) {
            stg((t + 1) & 1);
            __syncthreads();
        }
    }

    const unsigned zoff = (unsigned)z * (unsigned)M * (unsigned)N;
#pragma unroll
    for (int a = 0; a < 4; ++a) {
        const int m = m0 + wm + a * 16 + quad * 4;
#pragma unroll
        for (int b = 0; b < 2; ++b) {
            const int n = n0 + wn + b * 16 + l16;
#pragma unroll
            for (int r = 0; r < 4; ++r)
                Cp[zoff + (unsigned)(m + r) * N + n] = acc[a][b][r];
        }
    }
}

// ---------------------------------------------------------------------------
// MFMA bf16 GEMM (plain): C(M,N) = A(M,K) * B(N,K)^T, A/B bf16 row-major.
// OBF 0: C fp32 (+bias). OBF 1: C bf16 (scale, bias).
// Double-buffered LDS, XOR-swizzled (16B blocks), 1 barrier/iter, BK=32.
// ---------------------------------------------------------------------------
template <int BM, int BN, int OBF>
__global__ __launch_bounds__(256) void mfma_gemm(
    const ushort_t* __restrict__ Ab, const ushort_t* __restrict__ Bp,
    const float* __restrict__ bias, void* __restrict__ Cp_,
    int M, int N, int K, float oscale)
{
    constexpr int ASZ = BM * 32;
    constexpr int BSZ = BN * 32;
    constexpr int IA = BM / 64;
    constexpr int IB = BN / 64;
    constexpr int FM = BM / 32;
    constexpr int FN = BN / 32;
    __shared__ short lds[2 * (ASZ + BSZ)];

    const int tid = threadIdx.x;
    const int m0 = blockIdx.y * BM;
    const int n0 = blockIdx.x * BN;
    const int lane = tid & 63, wave = tid >> 6;
    const int l16 = lane & 15, quad = lane >> 4;
    const int wm = (wave >> 1) * (BM / 2);
    const int wn = (wave & 1) * (BN / 2);

    auto off = [](int r, int c) -> int {
        return ((r >> 1) << 6) + (((((r & 1) << 2) | c) ^ ((r >> 1) & 7)) << 3);
    };

    unsigned abase[IA]; int acs[IA], offA[IA];
#pragma unroll
    for (int i = 0; i < IA; ++i) {
        const int g = tid + i * 256;
        acs[i] = (g & 3) * 8;
        offA[i] = off(g >> 2, g & 3);
        abase[i] = (unsigned)(m0 + (g >> 2)) * K;
    }
    unsigned bbase[IB]; int bcs[IB], offB[IB];
#pragma unroll
    for (int i = 0; i < IB; ++i) {
        const int g = tid + i * 256;
        bcs[i] = (g & 3) * 8;
        offB[i] = off(g >> 2, g & 3);
        bbase[i] = (unsigned)(n0 + (g >> 2)) * K;
    }

    s16x8 aR[IA], bR[IB];
    auto loadg = [&](int t) {
        const int k = t * 32;
#pragma unroll
        for (int i = 0; i < IA; ++i)
            aR[i] = *(const s16x8*)(Ab + abase[i] + k + acs[i]);
#pragma unroll
        for (int i = 0; i < IB; ++i)
            bR[i] = *(const s16x8*)(Bp + bbase[i] + k + bcs[i]);
    };
    auto stg = [&](int buf) {
        short* A = lds + buf * (ASZ + BSZ);
        short* Bs = A + ASZ;
#pragma unroll
        for (int i = 0; i < IA; ++i) *(s16x8*)&A[offA[i]] = aR[i];
#pragma unroll
        for (int i = 0; i < IB; ++i) *(s16x8*)&Bs[offB[i]] = bR[i];
    };

    f32x4 acc[FM][FN];
#pragma unroll
    for (int a = 0; a < FM; ++a)
#pragma unroll
        for (int b = 0; b < FN; ++b)
            acc[a][b] = (f32x4){0.f, 0.f, 0.f, 0.f};

    loadg(0);
    stg(0);
    __syncthreads();
    const int nk = K >> 5;
    for (int t = 0; t < nk; ++t) {
        if (t + 1 < nk) loadg(t + 1);
        const short* A = lds + (t & 1) * (ASZ + BSZ);
        const short* Bs = A + ASZ;
        s16x8 af[FM], bfv[FN];
#pragma unroll
        for (int f = 0; f < FM; ++f)
            af[f] = *(const s16x8*)&A[off(wm + f * 16 + l16, quad)];
#pragma unroll
        for (int f = 0; f < FN; ++f)
            bfv[f] = *(const s16x8*)&Bs[off(wn + f * 16 + l16, quad)];
#pragma unroll
        for (int a = 0; a < FM; ++a)
#pragma unroll
            for (int b = 0; b < FN; ++b)
                acc[a][b] = __builtin_amdgcn_mfma_f32_16x16x32_bf16(
                    af[a], bfv[b], acc[a][b], 0, 0, 0);
        if (t + 1 < nk) {
            stg((t + 1) & 1);
            __syncthreads();
        }
    }

#pragma unroll
    for (int a = 0; a < FM; ++a) {
        const int m = m0 + wm + a * 16 + quad * 4;
#pragma unroll
        for (int b = 0; b < FN; ++b) {
            const int n = n0 + wn + b * 16 + l16;
            const float bv = bias ? bias[n] : 0.f;
#pragma unroll
            for (int r = 0; r < 4; ++r) {
                const float val = acc[a][b][r] * oscale + bv;
                if constexpr (OBF)
                    ((ushort_t*)Cp_)[(unsigned)(m + r) * N + n] = f2bf(val);
                else
                    ((float*)Cp_)[(unsigned)(m + r) * N + n] = val;
            }
        }
    }
}

// ---------------------------------------------------------------------------
// LayerNorm + ReLU6 with fused split-K reduction + conv bias. dst bf16.
// ---------------------------------------------------------------------------
__global__ __launch_bounds__(256) void ln_relu6_kernel(
    ushort_t* __restrict__ dst, const float* __restrict__ src, unsigned pstride,
    int np, const float* __restrict__ cb, const float* __restrict__ g,
    const float* __restrict__ bta)
{
    const int row = blockIdx.x * 4 + (threadIdx.x >> 6);
    const int lane = threadIdx.x & 63;
    float v[8];
#pragma unroll
    for (int j = 0; j < 8; ++j) v[j] = cb[lane + 64 * j];
    const float* p = src + (size_t)row * DIM;
    for (int ip = 0; ip < np; ++ip) {
#pragma unroll
        for (int j = 0; j < 8; ++j) v[j] += p[lane + 64 * j];
        p += pstride;
    }
    float s1 = 0.f, s2 = 0.f;
#pragma unroll
    for (int j = 0; j < 8; ++j) { s1 += v[j]; s2 += v[j] * v[j]; }
#pragma unroll
    for (int off = 32; off; off >>= 1) {
        s1 += __shfl_xor(s1, off, 64);
        s2 += __shfl_xor(s2, off, 64);
    }
    const float mean = s1 * (1.0f / DIM);
    const float var = s2 * (1.0f / DIM) - mean * mean;
    const float rstd = rsqrtf(var + 1e-5f);
    ushort_t* q = dst + (size_t)row * DIM;
#pragma unroll
    for (int j = 0; j < 8; ++j) {
        const int c = lane + 64 * j;
        float y = (v[j] - mean) * rstd * g[c] + bta[c];
        q[c] = f2bf(fminf(fmaxf(y, 0.0f), 6.0f));
    }
}

// ---------------------------------------------------------------------------
// vplus = v + dwconv3x3(v viewed as (B,C2,OW,OW)) + bias. bf16 in/out.
// ---------------------------------------------------------------------------
__global__ __launch_bounds__(256) void vplus_kernel(
    const ushort_t* __restrict__ vbuf, const float* __restrict__ lw,
    const float* __restrict__ lb, ushort_t* __restrict__ out, int lOW, int lL)
{
    const int idx = blockIdx.x * 256 + threadIdx.x;
    const int c = idx & 255;
    const int pix = (idx >> 8) & ((1 << lL) - 1);
    const int b = idx >> (8 + lL);
    const int OW = 1 << lOW;
    const int y = pix >> lOW, x = pix & (OW - 1);
    float acc = lb[c];
#pragma unroll
    for (int dy = -1; dy <= 1; ++dy) {
        const int ny = y + dy;
        if ((unsigned)ny >= (unsigned)OW) continue;
#pragma unroll
        for (int dx = -1; dx <= 1; ++dx) {
            const int nx = x + dx;
            if ((unsigned)nx >= (unsigned)OW) continue;
            acc += bf2f(vbuf[(((unsigned)(b << lL) + ny * OW + nx) << 8) + c]) *
                   lw[c * 9 + (dy + 1) * 3 + (dx + 1)];
        }
    }
    out[idx] = f2bf(bf2f(vbuf[idx]) + acc);
}

// ---------------------------------------------------------------------------
// MFMA attention, all operands bf16 (Q pre-scaled by 0.125 in q-projection).
// ---------------------------------------------------------------------------
template <int L>
__global__ __launch_bounds__(256) void attn_mfma(
    const ushort_t* __restrict__ qbuf, const ushort_t* __restrict__ kbuf,
    const ushort_t* __restrict__ vbuf, ushort_t* __restrict__ xbuf,
    int hoff, int coff)
{
    constexpr int SP = L + 12;
    constexpr int NV = L / 64;
    __shared__ float S[16][SP];
    __shared__ float invs[16];
    __shared__ alignas(16) short Qs[16][72];
    __shared__ alignas(16) short KV[64][72];

    const int tid = threadIdx.x;
    const int qt = blockIdx.x;
    const int h = blockIdx.y;
    const int b = blockIdx.z;
    const int lane = tid & 63, wave = tid >> 6;
    const int l16 = lane & 15, quad = lane >> 4;

    {
        const int r = tid >> 4, d0 = (tid & 15) * 4;
        int qi = qt * 16 + r; if (qi > QN - 1) qi = QN - 1;
        *(s16x4*)&Qs[r][d0] = *(const s16x4*)(
            qbuf + ((unsigned)(b * QN + qi) * NHEAD + hoff + h) * HD + d0);
    }

    // ---- Phase A: S = Q K^T ----
    const int klr = tid >> 2, kd0 = (tid & 3) * 16;
    for (int l0 = 0; l0 < L; l0 += 64) {
        const unsigned src = (unsigned)(b * L + l0 + klr) * C2 + h * HD + kd0;
        const s16x8 x0 = *(const s16x8*)(kbuf + src);
        const s16x8 x1 = *(const s16x8*)(kbuf + src + 8);
        __syncthreads();
        *(s16x8*)&KV[klr][kd0] = x0;
        *(s16x8*)&KV[klr][kd0 + 8] = x1;
        __syncthreads();
        f32x4 sacc = (f32x4){0.f, 0.f, 0.f, 0.f};
#pragma unroll
        for (int c = 0; c < 2; ++c) {
            const s16x8 af = *(const s16x8*)&Qs[l16][c * 32 + quad * 8];
            const s16x8 bf = *(const s16x8*)&KV[wave * 16 + l16][c * 32 + quad * 8];
            sacc = __builtin_amdgcn_mfma_f32_16x16x32_bf16(af, bf, sacc, 0, 0, 0);
        }
        const int col = l0 + wave * 16 + l16;
#pragma unroll
        for (int r = 0; r < 4; ++r) S[quad * 4 + r][col] = sacc[r];
    }
    __syncthreads();

    // ---- Phase B: softmax ----
#pragma unroll
    for (int rr = 0; rr < 4; ++rr) {
        const int row = wave * 4 + rr;
        float v[NV];
#pragma unroll
        for (int k = 0; k < NV; ++k) v[k] = S[row][lane + 64 * k];
        float m = -1e30f;
#pragma unroll
        for (int k = 0; k < NV; ++k) m = fmaxf(m, v[k]);
#pragma unroll
        for (int off = 32; off; off >>= 1) m = fmaxf(m, __shfl_xor(m, off, 64));
        float s = 0.f;
#pragma unroll
        for (int k = 0; k < NV; ++k) {
            v[k] = __expf(v[k] - m);
            s += v[k];
        }
#pragma unroll
        for (int off = 32; off; off >>= 1) s += __shfl_xor(s, off, 64);
#pragma unroll
        for (int k = 0; k < NV; ++k) S[row][lane + 64 * k] = v[k];
        if (lane == 0) invs[row] = 1.0f / s;
    }

    // ---- Phase C: O = P V ----
    f32x4 oacc = (f32x4){0.f, 0.f, 0.f, 0.f};
    const int vl = tid >> 4, vd0 = (tid & 15) * 4;
    for (int l0 = 0; l0 < L; l0 += 64) {
        s16x4 vr[4];
#pragma unroll
        for (int p = 0; p < 4; ++p)
            vr[p] = *(const s16x4*)(
                vbuf + (unsigned)(b * L + l0 + p * 16 + vl) * C2 + h * HD + vd0);
        __syncthreads();
#pragma unroll
        for (int p = 0; p < 4; ++p) {
            const int ll = p * 16 + vl;
            KV[vd0 + 0][ll] = vr[p][0];
            KV[vd0 + 1][ll] = vr[p][1];
            KV[vd0 + 2][ll] = vr[p][2];
            KV[vd0 + 3][ll] = vr[p][3];
        }
        __syncthreads();
#pragma unroll
        for (int c = 0; c < 2; ++c) {
            const float4 p0 = *(const float4*)&S[l16][l0 + c * 32 + quad * 8];
            const float4 p1 = *(const float4*)&S[l16][l0 + c * 32 + quad * 8 + 4];
            const s16x8 af = pack8(p0, p1);
            const s16x8 bf = *(const s16x8*)&KV[wave * 16 + l16][c * 32 + quad * 8];
            oacc = __builtin_amdgcn_mfma_f32_16x16x32_bf16(af, bf, oacc, 0, 0, 0);
        }
    }

    const int dcol = wave * 16 + l16;
#pragma unroll
    for (int r = 0; r < 4; ++r) {
        const int q = quad * 4 + r;
        const int qi = qt * 16 + q;
        if (qi < QN) {
            const float val = oacc[r] * invs[q];
            const int flat = ((b * QN + qi) * NH2 + h) * HD + dcol;
            xbuf[(unsigned)(flat >> 8) * DIM + coff + (flat & 255)] = f2bf(val);
        }
    }
}

// ---------------------------------------------------------------------------
// Launcher
// ---------------------------------------------------------------------------
extern "C" void kernel_launch(void* const* d_in, const int* in_sizes, int n_in,
                              void* d_out, int out_size, void* d_ws, size_t ws_size,
                              hipStream_t stream)
{
    const float* query   = (const float*)d_in[0];
    const float* key     = (const float*)d_in[1];
    const float* value   = (const float*)d_in[2];
    const float* q_w     = (const float*)d_in[3];
    const float* sr1_1_w = (const float*)d_in[4];
    const float* sr1_1_b = (const float*)d_in[5];
    const float* n1_1_g  = (const float*)d_in[6];
    const float* n1_1_b  = (const float*)d_in[7];
    const float* sr1_2_w = (const float*)d_in[8];
    const float* sr1_2_b = (const float*)d_in[9];
    const float* n1_2_g  = (const float*)d_in[10];
    const float* n1_2_b  = (const float*)d_in[11];
    const float* sr2_1_w = (const float*)d_in[12];
    const float* sr2_1_b = (const float*)d_in[13];
    const float* n2_1_g  = (const float*)d_in[14];
    const float* n2_1_b  = (const float*)d_in[15];
    const float* sr2_2_w = (const float*)d_in[16];
    const float* sr2_2_b = (const float*)d_in[17];
    const float* n2_2_g  = (const float*)d_in[18];
    const float* n2_2_b  = (const float*)d_in[19];
    const float* k1_w    = (const float*)d_in[20];
    const float* v1_w    = (const float*)d_in[21];
    const float* k2_w    = (const float*)d_in[22];
    const float* v2_w    = (const float*)d_in[23];
    const float* lc1_w   = (const float*)d_in[24];
    const float* lc1_b   = (const float*)d_in[25];
    const float* lc2_w   = (const float*)d_in[26];
    const float* lc2_b   = (const float*)d_in[27];
    const float* proj_w  = (const float*)d_in[28];
    const float* proj_b  = (const float*)d_in[29];
    float* out = (float*)d_out;
    char* ws = (char*)d_ws;

    // --- workspace layout (bytes); total 81,461,248 <= ws ---
    float*    SCR  = (float*)(ws + 0);            // 16.78 MB fp32, reused 4x
    ushort_t* WT1K = (ushort_t*)(ws + 16777216);  // 512x8192 bf16
    ushort_t* WT1V = (ushort_t*)(ws + 25165824);
    ushort_t* WT2K = (ushort_t*)(ws + 33554432);  // 512x2048 bf16
    ushort_t* WT2V = (ushort_t*)(ws + 35651584);
    ushort_t* KEY1 = (ushort_t*)(ws + 37748736);  // 2048x512 bf16
    ushort_t* VAL1 = (ushort_t*)(ws + 39845888);
    ushort_t* KEY2 = (ushort_t*)(ws + 41943040);  // 8192x512 bf16
    ushort_t* VAL2 = (ushort_t*)(ws + 50331648);
    ushort_t* QRYB = (ushort_t*)(ws + 58720256);  // 1600x512 bf16
    ushort_t* WQ   = (ushort_t*)(ws + 60358656);
    ushort_t* WK1  = (ushort_t*)(ws + 60882944);
    ushort_t* WV1  = (ushort_t*)(ws + 61145088);
    ushort_t* WK2  = (ushort_t*)(ws + 61407232);
    ushort_t* WV2  = (ushort_t*)(ws + 61669376);
    ushort_t* WP   = (ushort_t*)(ws + 61931520);
    ushort_t* QBUF = (ushort_t*)(ws + 62455808);  // 1600x512 bf16
    ushort_t* XBUF = (ushort_t*)(ws + 64094208);
    ushort_t* K1   = (ushort_t*)(ws + 65732608);  // 2048x256 bf16
    ushort_t* V1   = (ushort_t*)(ws + 66781184);
    ushort_t* VP1  = (ushort_t*)(ws + 67829760);
    ushort_t* K2   = (ushort_t*)(ws + 68878336);  // 8192x256 bf16
    ushort_t* V2   = (ushort_t*)(ws + 73072640);
    ushort_t* VP2  = (ushort_t*)(ws + 77266944);

    // 1) conversions + weight transposes
    cvt_f2b<<<400, 256, 0, stream>>>(query, QRYB, 102400);
    cvt_f2b<<<128, 256, 0, stream>>>(q_w, WQ, 32768);
    cvt_f2b<<<64, 256, 0, stream>>>(k1_w, WK1, 16384);
    cvt_f2b<<<64, 256, 0, stream>>>(v1_w, WV1, 16384);
    cvt_f2b<<<64, 256, 0, stream>>>(k2_w, WK2, 16384);
    cvt_f2b<<<64, 256, 0, stream>>>(v2_w, WV2, 16384);
    cvt_f2b<<<128, 256, 0, stream>>>(proj_w, WP, 32768);
    wtrans_kernel<<<512, 256, 0, stream>>>(sr1_1_w, WT1K, 16, 4);
    wtrans_kernel<<<512, 256, 0, stream>>>(sr1_2_w, WT1V, 16, 4);
    wtrans_kernel<<<512, 256, 0, stream>>>(sr2_1_w, WT2K, 4, 2);
    wtrans_kernel<<<512, 256, 0, stream>>>(sr2_2_w, WT2V, 4, 2);

    // 2) conv GEMMs (XCD-swizzled, BK=64) + fused-reduction LN -> bf16
    // conv1: M=2048 (lMT=4, 16 m-tiles), split-K z=4 (klen=2048): 512 blocks
    conv_gemm<<<512, 256, 0, stream>>>(key, WT1K, SCR, 2048, 512, 8192, 2048, 4, 2, 4);
    ln_relu6_kernel<<<512, 256, 0, stream>>>(KEY1, SCR, 1048576u, 4, sr1_1_b, n1_1_g, n1_1_b);
    conv_gemm<<<512, 256, 0, stream>>>(value, WT1V, SCR, 2048, 512, 8192, 2048, 4, 2, 4);
    ln_relu6_kernel<<<512, 256, 0, stream>>>(VAL1, SCR, 1048576u, 4, sr1_2_b, n1_2_g, n1_2_b);
    // conv2: M=8192 (lMT=6, 64 m-tiles), z=1: 512 blocks
    conv_gemm<<<512, 256, 0, stream>>>(key, WT2K, SCR, 8192, 512, 2048, 2048, 5, 1, 6);
    ln_relu6_kernel<<<2048, 256, 0, stream>>>(KEY2, SCR, 0u, 1, sr2_1_b, n2_1_g, n2_1_b);
    conv_gemm<<<512, 256, 0, stream>>>(value, WT2V, SCR, 8192, 512, 2048, 2048, 5, 1, 6);
    ln_relu6_kernel<<<2048, 256, 0, stream>>>(VAL2, SCR, 0u, 1, sr2_2_b, n2_2_g, n2_2_b);

    // 3) q projection (scale 0.125 folded in), bf16 out
    mfma_gemm<64, 64, 1><<<dim3(8, 25, 1), 256, 0, stream>>>(
        QRYB, WQ, nullptr, QBUF, 1600, 512, 512, 0.125f);

    // 4) k/v head projections, bf16 out
    mfma_gemm<64, 64, 1><<<dim3(4, 32, 1), 256, 0, stream>>>(
        KEY1, WK1, nullptr, K1, 2048, 256, 512, 1.0f);
    mfma_gemm<64, 64, 1><<<dim3(4, 32, 1), 256, 0, stream>>>(
        VAL1, WV1, nullptr, V1, 2048, 256, 512, 1.0f);
    mfma_gemm<64, 64, 1><<<dim3(4, 128, 1), 256, 0, stream>>>(
        KEY2, WK2, nullptr, K2, 8192, 256, 512, 1.0f);
    mfma_gemm<64, 64, 1><<<dim3(4, 128, 1), 256, 0, stream>>>(
        VAL2, WV2, nullptr, V2, 8192, 256, 512, 1.0f);

    // 5) v + local dwconv (bf16)
    vplus_kernel<<<2048, 256, 0, stream>>>(V1, lc1_w, lc1_b, VP1, 4, 8);
    vplus_kernel<<<8192, 256, 0, stream>>>(V2, lc2_w, lc2_b, VP2, 5, 10);

    // 6) attention (MFMA, bf16)
    attn_mfma<256><<<dim3(13, 4, 8), 256, 0, stream>>>(QBUF, K1, VP1, XBUF, 0, 0);
    attn_mfma<1024><<<dim3(13, 4, 8), 256, 0, stream>>>(QBUF, K2, VP2, XBUF, 4, 256);

    // 7) final projection + bias -> fp32 out
    mfma_gemm<64, 64, 0><<<dim3(8, 25, 1), 256, 0, stream>>>(
        XBUF, WP, proj_b, out, 1600, 512, 512, 1.0f);
}

// Round 6
// 479.606 us; speedup vs baseline: 4.0643x; 1.1342x over previous
//
#include <hip/hip_runtime.h>
#include <cstddef>

// Problem constants
#define QN   200
#define DIM  512
#define NHEAD 8
#define HD   64
#define C2   256
#define NH2  4
#define NTOK 4096   // 64*64

typedef unsigned short ushort_t;
typedef short s16x4 __attribute__((ext_vector_type(4)));
typedef short s16x8 __attribute__((ext_vector_type(8)));   // 8 bf16 (4 VGPRs)
typedef float f32x4 __attribute__((ext_vector_type(4)));   // MFMA accumulator

__device__ __forceinline__ unsigned short f2bf(float f) {
    unsigned int u = __float_as_uint(f);
    u += 0x7fffu + ((u >> 16) & 1u);   // round-to-nearest-even
    return (unsigned short)(u >> 16);
}
__device__ __forceinline__ float bf2f(unsigned short u) {
    return __uint_as_float(((unsigned int)u) << 16);
}
__device__ __forceinline__ s16x8 pack8(float4 x, float4 y) {
    s16x8 v;
    v[0] = (short)f2bf(x.x); v[1] = (short)f2bf(x.y);
    v[2] = (short)f2bf(x.z); v[3] = (short)f2bf(x.w);
    v[4] = (short)f2bf(y.x); v[5] = (short)f2bf(y.y);
    v[6] = (short)f2bf(y.z); v[7] = (short)f2bf(y.w);
    return v;
}

// ---------------------------------------------------------------------------
// fp32 -> bf16 elementwise (n8 = n/8 groups); used for the big images
// ---------------------------------------------------------------------------
__global__ __launch_bounds__(256) void cvt_f2b(
    const float* __restrict__ src, ushort_t* __restrict__ dst, int n8)
{
    const int i = blockIdx.x * 256 + threadIdx.x;
    if (i >= n8) return;
    const float4 a = ((const float4*)src)[i * 2];
    const float4 b = ((const float4*)src)[i * 2 + 1];
    ((s16x8*)dst)[i] = pack8(a, b);
}

// ---------------------------------------------------------------------------
// Merged small fp32->bf16 conversions (7 jobs, one launch)
// ---------------------------------------------------------------------------
struct CDesc { const float* s; ushort_t* d; };
struct CPack { CDesc c[7]; int bound[7]; };
__global__ __launch_bounds__(256) void prep_kernel(CPack pk)
{
    const int bid = blockIdx.x;
    int idx = 0;
#pragma unroll
    for (int i = 0; i < 6; ++i) idx += (bid >= pk.bound[i]);
    const int base = idx ? pk.bound[idx - 1] : 0;
    const int i = (bid - base) * 256 + threadIdx.x;
    const float4 a = ((const float4*)pk.c[idx].s)[i * 2];
    const float4 b = ((const float4*)pk.c[idx].s)[i * 2 + 1];
    ((s16x8*)pk.c[idx].d)[i] = pack8(a, b);
}

// ---------------------------------------------------------------------------
// Weight transpose: w (512, 512, KK) fp32 -> wt (512, KK*512) bf16, k'=p*512+ci
// ---------------------------------------------------------------------------
__global__ __launch_bounds__(256) void wtrans_kernel(
    const float* __restrict__ w, ushort_t* __restrict__ wt, int KK, int lKK)
{
    __shared__ float tile[512 * 17];
    const int c = blockIdx.x;
    const int K = KK << 9;
    const float* src = w + (size_t)c * K;
    ushort_t* dst = wt + (size_t)c * K;
    for (int i = threadIdx.x; i < K; i += 256) {
        int ci = i >> lKK, p = i & (KK - 1);
        tile[ci * (KK + 1) + p] = src[i];
    }
    __syncthreads();
    for (int i = threadIdx.x; i < K; i += 256) {
        int p = i >> 9, ci = i & 511;
        dst[i] = f2bf(tile[ci * (KK + 1) + p]);
    }
}

// ---------------------------------------------------------------------------
// Conv-patch GEMM (MFMA bf16, A is bf16 image): C = gather(A)(M,K) * B(512,K)^T
// BM=128, BN=64, BK=64. XCD-aware 1-D swizzle (8 n-tile blocks sharing an
// A M-slice land on one XCD). fp32 partials at Cp + z*M*N.
// ---------------------------------------------------------------------------
__global__ __launch_bounds__(256) void conv_gemm(
    const ushort_t* __restrict__ Ap, const ushort_t* __restrict__ Bp,
    float* __restrict__ Cp, int M, int N, int K, int klen,
    int lOW, int ls, int lMT)
{
    constexpr int ASZ = 128 * 64;
    constexpr int BSZ = 64 * 64;
    __shared__ short lds[2 * (ASZ + BSZ)];

    const int tid = threadIdx.x;
    const int bid = blockIdx.x;
    const int xcd = bid & 7;
    const int j = bid >> 3;
    const int nt = j & 7;
    const int mz = (j >> 3) * 8 + xcd;
    const int mt = mz & ((1 << lMT) - 1);
    const int z = mz >> lMT;
    const int m0 = mt * 128, n0 = nt * 64;
    const int kstart = z * klen;

    const int lane = tid & 63, wave = tid >> 6;
    const int l16 = lane & 15, quad = lane >> 4;
    const int wm = (wave >> 1) * 64;
    const int wn = (wave & 1) * 32;

    auto off = [](int r, int c) -> int {
        return (r << 6) + ((c ^ (r & 7)) << 3);
    };

    unsigned abase[4]; int offA[4], acx[4];
#pragma unroll
    for (int i = 0; i < 4; ++i) {
        const int g = tid + i * 256;
        const int r = g >> 3, c = g & 7;
        acx[i] = c * 8;
        offA[i] = off(r, c);
        const int OW = 1 << lOW;
        const int m = m0 + r;
        const int bidx = m >> (2 * lOW);
        const int pix = m & (OW * OW - 1);
        const int oy = pix >> lOW, ox = pix & (OW - 1);
        abase[i] = (unsigned)(bidx * NTOK + (oy << ls) * 64 + (ox << ls)) << 9;
    }
    unsigned bbase[2]; int offB[2], bcx[2];
#pragma unroll
    for (int i = 0; i < 2; ++i) {
        const int g = tid + i * 256;
        const int r = g >> 3, c = g & 7;
        bcx[i] = c * 8;
        offB[i] = off(r, c);
        bbase[i] = (unsigned)(n0 + r) * K;
    }

    s16x8 aR[4], bR[2];
    auto loadg = [&](int t) {
        const int k0 = kstart + t * 64;
#pragma unroll
        for (int i = 0; i < 4; ++i) {
            const int k = k0 + acx[i];
            const int p = k >> 9;
            const int ky = p >> ls, kx = p & ((1 << ls) - 1);
            const unsigned o = abase[i] + ((unsigned)(ky * 64 + kx) << 9) + (k & 511);
            aR[i] = *(const s16x8*)(Ap + o);
        }
#pragma unroll
        for (int i = 0; i < 2; ++i)
            bR[i] = *(const s16x8*)(Bp + bbase[i] + k0 + bcx[i]);
    };
    auto stg = [&](int buf) {
        short* A = lds + buf * (ASZ + BSZ);
        short* Bs = A + ASZ;
#pragma unroll
        for (int i = 0; i < 4; ++i) *(s16x8*)&A[offA[i]] = aR[i];
#pragma unroll
        for (int i = 0; i < 2; ++i) *(s16x8*)&Bs[offB[i]] = bR[i];
    };

    f32x4 acc[4][2];
#pragma unroll
    for (int a = 0; a < 4; ++a)
#pragma unroll
        for (int b = 0; b < 2; ++b)
            acc[a][b] = (f32x4){0.f, 0.f, 0.f, 0.f};

    loadg(0);
    stg(0);
    __syncthreads();
    const int nk = klen >> 6;
    for (int t = 0; t < nk; ++t) {
        if (t + 1 < nk) loadg(t + 1);
        const short* A = lds + (t & 1) * (ASZ + BSZ);
        const short* Bs = A + ASZ;
#pragma unroll
        for (int kk = 0; kk < 2; ++kk) {
            s16x8 af[4], bf[2];
#pragma unroll
            for (int f = 0; f < 4; ++f)
                af[f] = *(const s16x8*)&A[off(wm + f * 16 + l16, quad + kk * 4)];
#pragma unroll
            for (int f = 0; f < 2; ++f)
                bf[f] = *(const s16x8*)&Bs[off(wn + f * 16 + l16, quad + kk * 4)];
#pragma unroll
            for (int a = 0; a < 4; ++a)
#pragma unroll
                for (int b = 0; b < 2; ++b)
                    acc[a][b] = __builtin_amdgcn_mfma_f32_16x16x32_bf16(
                        af[a], bf[b], acc[a][b], 0, 0, 0);
        }
        if (t + 1 < nk) {
            stg((t + 1) & 1);
            __syncthreads();
        }
    }

    const unsigned zoff = (unsigned)z * (unsigned)M * (unsigned)N;
#pragma unroll
    for (int a = 0; a < 4; ++a) {
        const int m = m0 + wm + a * 16 + quad * 4;
#pragma unroll
        for (int b = 0; b < 2; ++b) {
            const int n = n0 + wn + b * 16 + l16;
#pragma unroll
            for (int r = 0; r < 4; ++r)
                Cp[zoff + (unsigned)(m + r) * N + n] = acc[a][b][r];
        }
    }
}

// ---------------------------------------------------------------------------
// 64x64-tile, K=512 GEMM body (bf16 in; OBF 1: bf16 out, 0: fp32 out + bias)
// ---------------------------------------------------------------------------
template <int OBF>
__device__ __forceinline__ void gemm64_k512(
    short* lds, const ushort_t* __restrict__ Ab, const ushort_t* __restrict__ Bp,
    const float* __restrict__ bias, void* __restrict__ Cp_,
    int m0, int n0, int N, float oscale)
{
    const int tid = threadIdx.x;
    const int lane = tid & 63, wave = tid >> 6;
    const int l16 = lane & 15, quad = lane >> 4;
    const int wm = (wave >> 1) * 32;
    const int wn = (wave & 1) * 32;

    auto off = [](int r, int c) -> int {
        return ((r >> 1) << 6) + (((((r & 1) << 2) | c) ^ ((r >> 1) & 7)) << 3);
    };

    const int cs = (tid & 3) * 8;
    const int ofA = off(tid >> 2, tid & 3);
    const unsigned ab = (unsigned)(m0 + (tid >> 2)) * 512;
    const unsigned bb = (unsigned)(n0 + (tid >> 2)) * 512;

    s16x8 aR, bR;
    auto loadg = [&](int t) {
        aR = *(const s16x8*)(Ab + ab + t * 32 + cs);
        bR = *(const s16x8*)(Bp + bb + t * 32 + cs);
    };
    auto stg = [&](int buf) {
        short* A = lds + buf * 4096;
        short* Bs = A + 2048;
        *(s16x8*)&A[ofA] = aR;
        *(s16x8*)&Bs[ofA] = bR;
    };

    f32x4 acc[2][2];
#pragma unroll
    for (int a = 0; a < 2; ++a)
#pragma unroll
        for (int b = 0; b < 2; ++b)
            acc[a][b] = (f32x4){0.f, 0.f, 0.f, 0.f};

    loadg(0); stg(0); __syncthreads();
#pragma unroll 1
    for (int t = 0; t < 16; ++t) {
        if (t + 1 < 16) loadg(t + 1);
        const short* A = lds + (t & 1) * 4096;
        const short* Bs = A + 2048;
        s16x8 af[2], bfv[2];
#pragma unroll
        for (int f = 0; f < 2; ++f)
            af[f] = *(const s16x8*)&A[off(wm + f * 16 + l16, quad)];
#pragma unroll
        for (int f = 0; f < 2; ++f)
            bfv[f] = *(const s16x8*)&Bs[off(wn + f * 16 + l16, quad)];
#pragma unroll
        for (int a = 0; a < 2; ++a)
#pragma unroll
            for (int b = 0; b < 2; ++b)
                acc[a][b] = __builtin_amdgcn_mfma_f32_16x16x32_bf16(
                    af[a], bfv[b], acc[a][b], 0, 0, 0);
        if (t + 1 < 16) { stg((t + 1) & 1); __syncthreads(); }
    }

#pragma unroll
    for (int a = 0; a < 2; ++a) {
        const int m = m0 + wm + a * 16 + quad * 4;
#pragma unroll
        for (int b = 0; b < 2; ++b) {
            const int n = n0 + wn + b * 16 + l16;
            const float bv = bias ? bias[n] : 0.f;
#pragma unroll
            for (int r = 0; r < 4; ++r) {
                const float val = acc[a][b][r] * oscale + bv;
                if constexpr (OBF)
                    ((ushort_t*)Cp_)[(unsigned)(m + r) * N + n] = f2bf(val);
                else
                    ((float*)Cp_)[(unsigned)(m + r) * N + n] = val;
            }
        }
    }
}

// Merged q/k1/v1/k2/v2 projections (one launch, 1480 blocks)
struct PDesc { const ushort_t* A; const ushort_t* B; ushort_t* C; int lnT; float scale; };
struct PPack { PDesc d[5]; int bound[5]; };
__global__ __launch_bounds__(256) void proj_gemm(PPack pk)
{
    __shared__ short lds[8192];
    const int bid = blockIdx.x;
    int idx = 0;
#pragma unroll
    for (int i = 0; i < 4; ++i) idx += (bid >= pk.bound[i]);
    const PDesc d = pk.d[idx];
    const int base = idx ? pk.bound[idx - 1] : 0;
    const int loc = bid - base;
    const int nt = loc & ((1 << d.lnT) - 1);
    const int mt = loc >> d.lnT;
    gemm64_k512<1>(lds, d.A, d.B, nullptr, d.C, mt * 64, nt * 64, 64 << d.lnT, d.scale);
}

// Final projection: fp32 out + bias, 200 blocks
__global__ __launch_bounds__(256) void final_gemm(
    const ushort_t* __restrict__ A, const ushort_t* __restrict__ B,
    const float* __restrict__ bias, float* __restrict__ C)
{
    __shared__ short lds[8192];
    const int m0 = (blockIdx.x >> 3) * 64;
    const int n0 = (blockIdx.x & 7) * 64;
    gemm64_k512<0>(lds, A, B, bias, C, m0, n0, 512, 1.0f);
}

// ---------------------------------------------------------------------------
// LayerNorm + ReLU6 with fused split-K reduction + conv bias. dst bf16.
// ---------------------------------------------------------------------------
__global__ __launch_bounds__(256) void ln_relu6_kernel(
    ushort_t* __restrict__ dst, const float* __restrict__ src, unsigned pstride,
    int np, const float* __restrict__ cb, const float* __restrict__ g,
    const float* __restrict__ bta)
{
    const int row = blockIdx.x * 4 + (threadIdx.x >> 6);
    const int lane = threadIdx.x & 63;
    float v[8];
#pragma unroll
    for (int j = 0; j < 8; ++j) v[j] = cb[lane + 64 * j];
    const float* p = src + (size_t)row * DIM;
    for (int ip = 0; ip < np; ++ip) {
#pragma unroll
        for (int j = 0; j < 8; ++j) v[j] += p[lane + 64 * j];
        p += pstride;
    }
    float s1 = 0.f, s2 = 0.f;
#pragma unroll
    for (int j = 0; j < 8; ++j) { s1 += v[j]; s2 += v[j] * v[j]; }
#pragma unroll
    for (int off = 32; off; off >>= 1) {
        s1 += __shfl_xor(s1, off, 64);
        s2 += __shfl_xor(s2, off, 64);
    }
    const float mean = s1 * (1.0f / DIM);
    const float var = s2 * (1.0f / DIM) - mean * mean;
    const float rstd = rsqrtf(var + 1e-5f);
    ushort_t* q = dst + (size_t)row * DIM;
#pragma unroll
    for (int j = 0; j < 8; ++j) {
        const int c = lane + 64 * j;
        float y = (v[j] - mean) * rstd * g[c] + bta[c];
        q[c] = f2bf(fminf(fmaxf(y, 0.0f), 6.0f));
    }
}

// ---------------------------------------------------------------------------
// vplus = v + dwconv3x3 + bias, both branches in one launch
// ---------------------------------------------------------------------------
__device__ __forceinline__ void vplus_body(
    const ushort_t* __restrict__ vbuf, const float* __restrict__ lw,
    const float* __restrict__ lb, ushort_t* __restrict__ out,
    int lOW, int lL, int blk)
{
    const int idx = blk * 256 + threadIdx.x;
    const int c = idx & 255;
    const int pix = (idx >> 8) & ((1 << lL) - 1);
    const int b = idx >> (8 + lL);
    const int OW = 1 << lOW;
    const int y = pix >> lOW, x = pix & (OW - 1);
    float acc = lb[c];
#pragma unroll
    for (int dy = -1; dy <= 1; ++dy) {
        const int ny = y + dy;
        if ((unsigned)ny >= (unsigned)OW) continue;
#pragma unroll
        for (int dx = -1; dx <= 1; ++dx) {
            const int nx = x + dx;
            if ((unsigned)nx >= (unsigned)OW) continue;
            acc += bf2f(vbuf[(((unsigned)(b << lL) + ny * OW + nx) << 8) + c]) *
                   lw[c * 9 + (dy + 1) * 3 + (dx + 1)];
        }
    }
    out[idx] = f2bf(bf2f(vbuf[idx]) + acc);
}

__global__ __launch_bounds__(256) void vplus2_kernel(
    const ushort_t* v1, const float* w1, const float* b1, ushort_t* o1,
    const ushort_t* v2, const float* w2, const float* b2, ushort_t* o2)
{
    const int bid = blockIdx.x;
    if (bid < 2048) vplus_body(v1, w1, b1, o1, 4, 8, bid);
    else            vplus_body(v2, w2, b2, o2, 5, 10, bid - 2048);
}

// ---------------------------------------------------------------------------
// MFMA attention, all operands bf16 (Q pre-scaled by 0.125 in q-projection).
// ---------------------------------------------------------------------------
template <int L>
__global__ __launch_bounds__(256) void attn_mfma(
    const ushort_t* __restrict__ qbuf, const ushort_t* __restrict__ kbuf,
    const ushort_t* __restrict__ vbuf, ushort_t* __restrict__ xbuf,
    int hoff, int coff)
{
    constexpr int SP = L + 12;
    constexpr int NV = L / 64;
    __shared__ float S[16][SP];
    __shared__ float invs[16];
    __shared__ alignas(16) short Qs[16][72];
    __shared__ alignas(16) short KV[64][72];

    const int tid = threadIdx.x;
    const int qt = blockIdx.x;
    const int h = blockIdx.y;
    const int b = blockIdx.z;
    const int lane = tid & 63, wave = tid >> 6;
    const int l16 = lane & 15, quad = lane >> 4;

    {
        const int r = tid >> 4, d0 = (tid & 15) * 4;
        int qi = qt * 16 + r; if (qi > QN - 1) qi = QN - 1;
        *(s16x4*)&Qs[r][d0] = *(const s16x4*)(
            qbuf + ((unsigned)(b * QN + qi) * NHEAD + hoff + h) * HD + d0);
    }

    // ---- Phase A: S = Q K^T ----
    const int klr = tid >> 2, kd0 = (tid & 3) * 16;
    for (int l0 = 0; l0 < L; l0 += 64) {
        const unsigned src = (unsigned)(b * L + l0 + klr) * C2 + h * HD + kd0;
        const s16x8 x0 = *(const s16x8*)(kbuf + src);
        const s16x8 x1 = *(const s16x8*)(kbuf + src + 8);
        __syncthreads();
        *(s16x8*)&KV[klr][kd0] = x0;
        *(s16x8*)&KV[klr][kd0 + 8] = x1;
        __syncthreads();
        f32x4 sacc = (f32x4){0.f, 0.f, 0.f, 0.f};
#pragma unroll
        for (int c = 0; c < 2; ++c) {
            const s16x8 af = *(const s16x8*)&Qs[l16][c * 32 + quad * 8];
            const s16x8 bf = *(const s16x8*)&KV[wave * 16 + l16][c * 32 + quad * 8];
            sacc = __builtin_amdgcn_mfma_f32_16x16x32_bf16(af, bf, sacc, 0, 0, 0);
        }
        const int col = l0 + wave * 16 + l16;
#pragma unroll
        for (int r = 0; r < 4; ++r) S[quad * 4 + r][col] = sacc[r];
    }
    __syncthreads();

    // ---- Phase B: softmax ----
#pragma unroll
    for (int rr = 0; rr < 4; ++rr) {
        const int row = wave * 4 + rr;
        float v[NV];
#pragma unroll
        for (int k = 0; k < NV; ++k) v[k] = S[row][lane + 64 * k];
        float m = -1e30f;
#pragma unroll
        for (int k = 0; k < NV; ++k) m = fmaxf(m, v[k]);
#pragma unroll
        for (int off = 32; off; off >>= 1) m = fmaxf(m, __shfl_xor(m, off, 64));
        float s = 0.f;
#pragma unroll
        for (int k = 0; k < NV; ++k) {
            v[k] = __expf(v[k] - m);
            s += v[k];
        }
#pragma unroll
        for (int off = 32; off; off >>= 1) s += __shfl_xor(s, off, 64);
#pragma unroll
        for (int k = 0; k < NV; ++k) S[row][lane + 64 * k] = v[k];
        if (lane == 0) invs[row] = 1.0f / s;
    }

    // ---- Phase C: O = P V ----
    f32x4 oacc = (f32x4){0.f, 0.f, 0.f, 0.f};
    const int vl = tid >> 4, vd0 = (tid & 15) * 4;
    for (int l0 = 0; l0 < L; l0 += 64) {
        s16x4 vr[4];
#pragma unroll
        for (int p = 0; p < 4; ++p)
            vr[p] = *(const s16x4*)(
                vbuf + (unsigned)(b * L + l0 + p * 16 + vl) * C2 + h * HD + vd0);
        __syncthreads();
#pragma unroll
        for (int p = 0; p < 4; ++p) {
            const int ll = p * 16 + vl;
            KV[vd0 + 0][ll] = vr[p][0];
            KV[vd0 + 1][ll] = vr[p][1];
            KV[vd0 + 2][ll] = vr[p][2];
            KV[vd0 + 3][ll] = vr[p][3];
        }
        __syncthreads();
#pragma unroll
        for (int c = 0; c < 2; ++c) {
            const float4 p0 = *(const float4*)&S[l16][l0 + c * 32 + quad * 8];
            const float4 p1 = *(const float4*)&S[l16][l0 + c * 32 + quad * 8 + 4];
            const s16x8 af = pack8(p0, p1);
            const s16x8 bf = *(const s16x8*)&KV[wave * 16 + l16][c * 32 + quad * 8];
            oacc = __builtin_amdgcn_mfma_f32_16x16x32_bf16(af, bf, oacc, 0, 0, 0);
        }
    }

    const int dcol = wave * 16 + l16;
#pragma unroll
    for (int r = 0; r < 4; ++r) {
        const int q = quad * 4 + r;
        const int qi = qt * 16 + q;
        if (qi < QN) {
            const float val = oacc[r] * invs[q];
            const int flat = ((b * QN + qi) * NH2 + h) * HD + dcol;
            xbuf[(unsigned)(flat >> 8) * DIM + coff + (flat & 255)] = f2bf(val);
        }
    }
}

// ---------------------------------------------------------------------------
// Launcher
// ---------------------------------------------------------------------------
extern "C" void kernel_launch(void* const* d_in, const int* in_sizes, int n_in,
                              void* d_out, int out_size, void* d_ws, size_t ws_size,
                              hipStream_t stream)
{
    const float* query   = (const float*)d_in[0];
    const float* key     = (const float*)d_in[1];
    const float* value   = (const float*)d_in[2];
    const float* q_w     = (const float*)d_in[3];
    const float* sr1_1_w = (const float*)d_in[4];
    const float* sr1_1_b = (const float*)d_in[5];
    const float* n1_1_g  = (const float*)d_in[6];
    const float* n1_1_b  = (const float*)d_in[7];
    const float* sr1_2_w = (const float*)d_in[8];
    const float* sr1_2_b = (const float*)d_in[9];
    const float* n1_2_g  = (const float*)d_in[10];
    const float* n1_2_b  = (const float*)d_in[11];
    const float* sr2_1_w = (const float*)d_in[12];
    const float* sr2_1_b = (const float*)d_in[13];
    const float* n2_1_g  = (const float*)d_in[14];
    const float* n2_1_b  = (const float*)d_in[15];
    const float* sr2_2_w = (const float*)d_in[16];
    const float* sr2_2_b = (const float*)d_in[17];
    const float* n2_2_g  = (const float*)d_in[18];
    const float* n2_2_b  = (const float*)d_in[19];
    const float* k1_w    = (const float*)d_in[20];
    const float* v1_w    = (const float*)d_in[21];
    const float* k2_w    = (const float*)d_in[22];
    const float* v2_w    = (const float*)d_in[23];
    const float* lc1_w   = (const float*)d_in[24];
    const float* lc1_b   = (const float*)d_in[25];
    const float* lc2_w   = (const float*)d_in[26];
    const float* lc2_b   = (const float*)d_in[27];
    const float* proj_w  = (const float*)d_in[28];
    const float* proj_b  = (const float*)d_in[29];
    float* out = (float*)d_out;
    char* ws = (char*)d_ws;

    // --- workspace layout (bytes); total 79,691,776 ---
    ushort_t* IMGB = (ushort_t*)(ws + 0);          // 33.5 MB bf16 image (key->value)
    float*    SCR  = (float*)(ws + 33554432);      // 16.78 MB fp32 conv partials
    ushort_t* WT1  = (ushort_t*)(ws + 50331648);   // 8.4 MB (sr1_1 then sr1_2)
    ushort_t* KEY1 = (ushort_t*)(ws + 58720256);
    ushort_t* VAL1 = (ushort_t*)(ws + 60817408);
    ushort_t* KEY2 = (ushort_t*)(ws + 62914560);
    ushort_t* VAL2 = (ushort_t*)(ws + 71303168);   // ends 79,691,776
    ushort_t* WT2  = (ushort_t*)d_out;             // 2.1 MB in d_out (overwritten at end)
    // post-conv tensors live inside the dead IMGB region:
    ushort_t* QRYB = (ushort_t*)(ws + 0);          // 1600x512
    ushort_t* WQ   = (ushort_t*)(ws + 1638400);
    ushort_t* WK1  = (ushort_t*)(ws + 2162688);
    ushort_t* WV1  = (ushort_t*)(ws + 2424832);
    ushort_t* WK2  = (ushort_t*)(ws + 2686976);
    ushort_t* WV2  = (ushort_t*)(ws + 2949120);
    ushort_t* WP   = (ushort_t*)(ws + 3211264);
    ushort_t* QBUF = (ushort_t*)(ws + 3735552);
    ushort_t* XBUF = (ushort_t*)(ws + 5373952);
    ushort_t* K1   = (ushort_t*)(ws + 7012352);
    ushort_t* V1   = (ushort_t*)(ws + 8060928);
    ushort_t* VP1  = (ushort_t*)(ws + 9109504);
    ushort_t* K2   = (ushort_t*)(ws + 10158080);
    ushort_t* V2   = (ushort_t*)(ws + 14352384);
    ushort_t* VP2  = (ushort_t*)(ws + 18546688);   // ends 22,740,992 < 33,554,432

    // ---- key branch ----
    cvt_f2b<<<8192, 256, 0, stream>>>(key, IMGB, 2097152);
    wtrans_kernel<<<512, 256, 0, stream>>>(sr1_1_w, WT1, 16, 4);
    conv_gemm<<<512, 256, 0, stream>>>(IMGB, WT1, SCR, 2048, 512, 8192, 2048, 4, 2, 4);
    ln_relu6_kernel<<<512, 256, 0, stream>>>(KEY1, SCR, 1048576u, 4, sr1_1_b, n1_1_g, n1_1_b);
    wtrans_kernel<<<512, 256, 0, stream>>>(sr2_1_w, WT2, 4, 2);
    conv_gemm<<<512, 256, 0, stream>>>(IMGB, WT2, SCR, 8192, 512, 2048, 2048, 5, 1, 6);
    ln_relu6_kernel<<<2048, 256, 0, stream>>>(KEY2, SCR, 0u, 1, sr2_1_b, n2_1_g, n2_1_b);

    // ---- value branch (reuses IMGB, WT1, WT2, SCR) ----
    cvt_f2b<<<8192, 256, 0, stream>>>(value, IMGB, 2097152);
    wtrans_kernel<<<512, 256, 0, stream>>>(sr1_2_w, WT1, 16, 4);
    conv_gemm<<<512, 256, 0, stream>>>(IMGB, WT1, SCR, 2048, 512, 8192, 2048, 4, 2, 4);
    ln_relu6_kernel<<<512, 256, 0, stream>>>(VAL1, SCR, 1048576u, 4, sr1_2_b, n1_2_g, n1_2_b);
    wtrans_kernel<<<512, 256, 0, stream>>>(sr2_2_w, WT2, 4, 2);
    conv_gemm<<<512, 256, 0, stream>>>(IMGB, WT2, SCR, 8192, 512, 2048, 2048, 5, 1, 6);
    ln_relu6_kernel<<<2048, 256, 0, stream>>>(VAL2, SCR, 0u, 1, sr2_2_b, n2_2_g, n2_2_b);

    // ---- small conversions (into dead IMGB region) ----
    CPack cp;
    cp.c[0] = {query,  QRYB}; cp.c[1] = {q_w, WQ};  cp.c[2] = {k1_w, WK1};
    cp.c[3] = {v1_w,   WV1};  cp.c[4] = {k2_w, WK2}; cp.c[5] = {v2_w, WV2};
    cp.c[6] = {proj_w, WP};
    cp.bound[0] = 400; cp.bound[1] = 528; cp.bound[2] = 592; cp.bound[3] = 656;
    cp.bound[4] = 720; cp.bound[5] = 784; cp.bound[6] = 912;
    prep_kernel<<<912, 256, 0, stream>>>(cp);

    // ---- merged projections: q (scaled), k1, v1, k2, v2 ----
    PPack pp;
    pp.d[0] = {QRYB, WQ,  QBUF, 3, 0.125f};
    pp.d[1] = {KEY1, WK1, K1,   2, 1.0f};
    pp.d[2] = {VAL1, WV1, V1,   2, 1.0f};
    pp.d[3] = {KEY2, WK2, K2,   2, 1.0f};
    pp.d[4] = {VAL2, WV2, V2,   2, 1.0f};
    pp.bound[0] = 200; pp.bound[1] = 328; pp.bound[2] = 456; pp.bound[3] = 968;
    pp.bound[4] = 1480;
    proj_gemm<<<1480, 256, 0, stream>>>(pp);

    // ---- v + local dwconv (both branches) ----
    vplus2_kernel<<<10240, 256, 0, stream>>>(V1, lc1_w, lc1_b, VP1,
                                             V2, lc2_w, lc2_b, VP2);

    // ---- attention ----
    attn_mfma<256><<<dim3(13, 4, 8), 256, 0, stream>>>(QBUF, K1, VP1, XBUF, 0, 0);
    attn_mfma<1024><<<dim3(13, 4, 8), 256, 0, stream>>>(QBUF, K2, VP2, XBUF, 4, 256);

    // ---- final projection + bias -> fp32 out ----
    final_gemm<<<200, 256, 0, stream>>>(XBUF, WP, proj_b, out);
}

// Round 7
// 466.911 us; speedup vs baseline: 4.1748x; 1.0272x over previous
//
#include <hip/hip_runtime.h>
#include <cstddef>
#include <cstdint>

// Problem constants
#define QN   200
#define DIM  512
#define NHEAD 8
#define HD   64
#define C2   256
#define NH2  4
#define NTOK 4096   // 64*64

typedef unsigned short ushort_t;
typedef unsigned int u32;
typedef short s16x4 __attribute__((ext_vector_type(4)));
typedef short s16x8 __attribute__((ext_vector_type(8)));   // 8 bf16 (4 VGPRs)
typedef float f32x4 __attribute__((ext_vector_type(4)));   // MFMA accumulator

__device__ __forceinline__ unsigned short f2bf(float f) {
    unsigned int u = __float_as_uint(f);
    u += 0x7fffu + ((u >> 16) & 1u);   // round-to-nearest-even
    return (unsigned short)(u >> 16);
}
__device__ __forceinline__ float bf2f(unsigned short u) {
    return __uint_as_float(((unsigned int)u) << 16);
}
__device__ __forceinline__ s16x8 pack8(float4 x, float4 y) {
    s16x8 v;
    v[0] = (short)f2bf(x.x); v[1] = (short)f2bf(x.y);
    v[2] = (short)f2bf(x.z); v[3] = (short)f2bf(x.w);
    v[4] = (short)f2bf(y.x); v[5] = (short)f2bf(y.y);
    v[6] = (short)f2bf(y.z); v[7] = (short)f2bf(y.w);
    return v;
}

// global -> LDS 16B DMA (wave-uniform LDS base + lane*16)
__device__ __forceinline__ void gld16(const ushort_t* g, short* l) {
    __builtin_amdgcn_global_load_lds(
        (const __attribute__((address_space(1))) u32*)g,
        (__attribute__((address_space(3))) u32*)l, 16, 0, 0);
}

// ---------------------------------------------------------------------------
// All fp32 -> bf16 conversions in one launch (9 jobs)
// ---------------------------------------------------------------------------
struct CDesc { const float* s; ushort_t* d; };
struct CPack { CDesc c[9]; int bound[9]; };
__global__ __launch_bounds__(256) void cvt_all(CPack pk)
{
    const int bid = blockIdx.x;
    int idx = 0;
#pragma unroll
    for (int i = 0; i < 8; ++i) idx += (bid >= pk.bound[i]);
    const int base = idx ? pk.bound[idx - 1] : 0;
    const int i = (bid - base) * 256 + threadIdx.x;
    const float4 a = ((const float4*)pk.c[idx].s)[i * 2];
    const float4 b = ((const float4*)pk.c[idx].s)[i * 2 + 1];
    ((s16x8*)pk.c[idx].d)[i] = pack8(a, b);
}

// ---------------------------------------------------------------------------
// All 4 conv-weight transposes in one launch (512 blocks per job)
// w (512, 512, KK) fp32 -> wt (512, KK*512) bf16, k'=p*512+ci
// ---------------------------------------------------------------------------
struct WDesc { const float* s; ushort_t* d; int KK; int lKK; };
struct WPack { WDesc w[4]; };
__global__ __launch_bounds__(256) void wtrans4(WPack pk)
{
    __shared__ float tile[512 * 17];
    const WDesc d = pk.w[blockIdx.x >> 9];
    const int c = blockIdx.x & 511;
    const int KK = d.KK, lKK = d.lKK;
    const int K = KK << 9;
    const float* src = d.s + (size_t)c * K;
    ushort_t* dst = d.d + (size_t)c * K;
    for (int i = threadIdx.x; i < K; i += 256) {
        int ci = i >> lKK, p = i & (KK - 1);
        tile[ci * (KK + 1) + p] = src[i];
    }
    __syncthreads();
    for (int i = threadIdx.x; i < K; i += 256) {
        int p = i >> 9, ci = i & 511;
        dst[i] = f2bf(tile[ci * (KK + 1) + p]);
    }
}

// ---------------------------------------------------------------------------
// Conv-patch GEMM (MFMA bf16, A bf16 image): C = gather(A)(M,K) * B(512,K)^T
// 128x128 tile, BK=64, global_load_lds(16B) staging, single 32KB LDS buffer,
// 2 barriers/iter (m97 structure). XOR swizzle applied on the SOURCE address
// (DMA LDS side is lane-linear); fragment reads use the matching swizzle.
// Grid = 1024: [0,512) key image, [512,1024) value image. Within each half,
// XCD-aware: xcd=bid&7, j=bid>>3, nt=j&3, mz=(j>>2)*8+xcd, mt=mz&(2^lMT-1),
// z=mz>>lMT  -> the 4 blocks sharing an A M-slice land on one XCD.
// fp32 partials at Cp + z*M*512 (bias/reduction fused into LN).
// ---------------------------------------------------------------------------
__global__ __launch_bounds__(256) void conv_gemm(
    const ushort_t* __restrict__ ApK, const ushort_t* __restrict__ BpK,
    float* __restrict__ CpK,
    const ushort_t* __restrict__ ApV, const ushort_t* __restrict__ BpV,
    float* __restrict__ CpV,
    int M, int K, int klen, int lOW, int ls, int lMT)
{
    __shared__ short lds[16384];   // A: [0,8192) shorts, B: [8192,16384)

    const int tid = threadIdx.x;
    int bid = blockIdx.x;
    const ushort_t* Ap; const ushort_t* Bp; float* Cp;
    if (bid < 512) { Ap = ApK; Bp = BpK; Cp = CpK; }
    else           { Ap = ApV; Bp = BpV; Cp = CpV; bid -= 512; }

    const int xcd = bid & 7;
    const int j = bid >> 3;
    const int nt = j & 3;
    const int mz = (j >> 2) * 8 + xcd;
    const int mt = mz & ((1 << lMT) - 1);
    const int z = mz >> lMT;
    const int m0 = mt * 128, n0 = nt * 128;
    const int kstart = z * klen;

    const int lane = tid & 63, wave = tid >> 6;
    const int l16 = lane & 15, quad = lane >> 4;
    const int wm = (wave >> 1) * 64;
    const int wn = (wave & 1) * 64;

    // staging maps: slot g covers LDS 16B-block g; content row g>>3,
    // k-block (g&7)^(row&7) (source-side swizzle)
    unsigned abase[4]; int acb[4];
    const ushort_t* bptr[4];
    short* ldsA[4]; short* ldsB[4];
    const int OW = 1 << lOW;
#pragma unroll
    for (int i = 0; i < 4; ++i) {
        const int g = i * 256 + tid;
        const int r = g >> 3, c = g & 7;
        acb[i] = ((c ^ (r & 7)) << 3);
        const int m = m0 + r;
        const int bidx = m >> (2 * lOW);
        const int pix = m & (OW * OW - 1);
        const int oy = pix >> lOW, ox = pix & (OW - 1);
        abase[i] = (unsigned)(bidx * NTOK + (oy << ls) * 64 + (ox << ls)) << 9;
        bptr[i] = Bp + (unsigned)(n0 + r) * K + kstart + acb[i];
        ldsA[i] = lds + (i * 256 + wave * 64) * 8;
        ldsB[i] = lds + 8192 + (i * 256 + wave * 64) * 8;
    }

    f32x4 acc[4][4];
#pragma unroll
    for (int a = 0; a < 4; ++a)
#pragma unroll
        for (int b = 0; b < 4; ++b)
            acc[a][b] = (f32x4){0.f, 0.f, 0.f, 0.f};

    const int lsm = (1 << ls) - 1;
    const int nk = klen >> 6;
#pragma unroll 1
    for (int t = 0; t < nk; ++t) {
        const int k0 = kstart + (t << 6);
#pragma unroll
        for (int i = 0; i < 4; ++i) {
            const int k = k0 + acb[i];
            const int p = k >> 9;
            const int ky = p >> ls, kx = p & lsm;
            gld16(Ap + abase[i] + ((unsigned)(ky * 64 + kx) << 9) + (k & 511), ldsA[i]);
        }
#pragma unroll
        for (int i = 0; i < 4; ++i)
            gld16(bptr[i] + (t << 6), ldsB[i]);
        __syncthreads();   // drains vmcnt(0): DMA visible to all waves

#pragma unroll
        for (int kk = 0; kk < 2; ++kk) {
            const int sw = ((quad + kk * 4) ^ (l16 & 7)) << 3;
            s16x8 af[4], bfv[4];
#pragma unroll
            for (int f = 0; f < 4; ++f)
                af[f] = *(const s16x8*)&lds[(wm + f * 16 + l16) * 64 + sw];
#pragma unroll
            for (int f = 0; f < 4; ++f)
                bfv[f] = *(const s16x8*)&lds[8192 + (wn + f * 16 + l16) * 64 + sw];
#pragma unroll
            for (int a = 0; a < 4; ++a)
#pragma unroll
                for (int b = 0; b < 4; ++b)
                    acc[a][b] = __builtin_amdgcn_mfma_f32_16x16x32_bf16(
                        af[a], bfv[b], acc[a][b], 0, 0, 0);
        }
        __syncthreads();   // all frag reads done before next tile's DMA
    }

    float* __restrict__ Cz = Cp + (size_t)z * M * 512;
#pragma unroll
    for (int a = 0; a < 4; ++a) {
        const int m = m0 + wm + a * 16 + quad * 4;
#pragma unroll
        for (int b = 0; b < 4; ++b) {
            const int n = n0 + wn + b * 16 + l16;
#pragma unroll
            for (int r = 0; r < 4; ++r)
                Cz[(unsigned)(m + r) * 512 + n] = acc[a][b][r];
        }
    }
}

// ---------------------------------------------------------------------------
// 64x64-tile, K=512 GEMM body (bf16 in; OBF 1: bf16 out, 0: fp32 out + bias)
// ---------------------------------------------------------------------------
template <int OBF>
__device__ __forceinline__ void gemm64_k512(
    short* lds, const ushort_t* __restrict__ Ab, const ushort_t* __restrict__ Bp,
    const float* __restrict__ bias, void* __restrict__ Cp_,
    int m0, int n0, int N, float oscale)
{
    const int tid = threadIdx.x;
    const int lane = tid & 63, wave = tid >> 6;
    const int l16 = lane & 15, quad = lane >> 4;
    const int wm = (wave >> 1) * 32;
    const int wn = (wave & 1) * 32;

    auto off = [](int r, int c) -> int {
        return ((r >> 1) << 6) + (((((r & 1) << 2) | c) ^ ((r >> 1) & 7)) << 3);
    };

    const int cs = (tid & 3) * 8;
    const int ofA = off(tid >> 2, tid & 3);
    const unsigned ab = (unsigned)(m0 + (tid >> 2)) * 512;
    const unsigned bb = (unsigned)(n0 + (tid >> 2)) * 512;

    s16x8 aR, bR;
    auto loadg = [&](int t) {
        aR = *(const s16x8*)(Ab + ab + t * 32 + cs);
        bR = *(const s16x8*)(Bp + bb + t * 32 + cs);
    };
    auto stg = [&](int buf) {
        short* A = lds + buf * 4096;
        short* Bs = A + 2048;
        *(s16x8*)&A[ofA] = aR;
        *(s16x8*)&Bs[ofA] = bR;
    };

    f32x4 acc[2][2];
#pragma unroll
    for (int a = 0; a < 2; ++a)
#pragma unroll
        for (int b = 0; b < 2; ++b)
            acc[a][b] = (f32x4){0.f, 0.f, 0.f, 0.f};

    loadg(0); stg(0); __syncthreads();
#pragma unroll 1
    for (int t = 0; t < 16; ++t) {
        if (t + 1 < 16) loadg(t + 1);
        const short* A = lds + (t & 1) * 4096;
        const short* Bs = A + 2048;
        s16x8 af[2], bfv[2];
#pragma unroll
        for (int f = 0; f < 2; ++f)
            af[f] = *(const s16x8*)&A[off(wm + f * 16 + l16, quad)];
#pragma unroll
        for (int f = 0; f < 2; ++f)
            bfv[f] = *(const s16x8*)&Bs[off(wn + f * 16 + l16, quad)];
#pragma unroll
        for (int a = 0; a < 2; ++a)
#pragma unroll
            for (int b = 0; b < 2; ++b)
                acc[a][b] = __builtin_amdgcn_mfma_f32_16x16x32_bf16(
                    af[a], bfv[b], acc[a][b], 0, 0, 0);
        if (t + 1 < 16) { stg((t + 1) & 1); __syncthreads(); }
    }

#pragma unroll
    for (int a = 0; a < 2; ++a) {
        const int m = m0 + wm + a * 16 + quad * 4;
#pragma unroll
        for (int b = 0; b < 2; ++b) {
            const int n = n0 + wn + b * 16 + l16;
            const float bv = bias ? bias[n] : 0.f;
#pragma unroll
            for (int r = 0; r < 4; ++r) {
                const float val = acc[a][b][r] * oscale + bv;
                if constexpr (OBF)
                    ((ushort_t*)Cp_)[(unsigned)(m + r) * N + n] = f2bf(val);
                else
                    ((float*)Cp_)[(unsigned)(m + r) * N + n] = val;
            }
        }
    }
}

// Merged q/k1/v1/k2/v2 projections (one launch, 1480 blocks)
struct PDesc { const ushort_t* A; const ushort_t* B; ushort_t* C; int lnT; float scale; };
struct PPack { PDesc d[5]; int bound[5]; };
__global__ __launch_bounds__(256) void proj_gemm(PPack pk)
{
    __shared__ short lds[8192];
    const int bid = blockIdx.x;
    int idx = 0;
#pragma unroll
    for (int i = 0; i < 4; ++i) idx += (bid >= pk.bound[i]);
    const PDesc d = pk.d[idx];
    const int base = idx ? pk.bound[idx - 1] : 0;
    const int loc = bid - base;
    const int nt = loc & ((1 << d.lnT) - 1);
    const int mt = loc >> d.lnT;
    gemm64_k512<1>(lds, d.A, d.B, nullptr, d.C, mt * 64, nt * 64, 64 << d.lnT, d.scale);
}

// Final projection: fp32 out + bias, 200 blocks
__global__ __launch_bounds__(256) void final_gemm(
    const ushort_t* __restrict__ A, const ushort_t* __restrict__ B,
    const float* __restrict__ bias, float* __restrict__ C)
{
    __shared__ short lds[8192];
    const int m0 = (blockIdx.x >> 3) * 64;
    const int n0 = (blockIdx.x & 7) * 64;
    gemm64_k512<0>(lds, A, B, bias, C, m0, n0, 512, 1.0f);
}

// ---------------------------------------------------------------------------
// LayerNorm + ReLU6 with fused split-K reduction + conv bias; key+value pair
// in one launch (first `half` blocks = job 1). dst bf16.
// ---------------------------------------------------------------------------
__global__ __launch_bounds__(256) void ln2_kernel(
    ushort_t* __restrict__ d1, const float* __restrict__ s1,
    const float* __restrict__ cb1, const float* __restrict__ g1,
    const float* __restrict__ b1,
    ushort_t* __restrict__ d2, const float* __restrict__ s2,
    const float* __restrict__ cb2, const float* __restrict__ g2,
    const float* __restrict__ b2,
    unsigned pstride, int np, int half)
{
    ushort_t* dst; const float* src; const float* cb; const float* g; const float* bta;
    int blk = blockIdx.x;
    if (blk < half) { dst = d1; src = s1; cb = cb1; g = g1; bta = b1; }
    else            { dst = d2; src = s2; cb = cb2; g = g2; bta = b2; blk -= half; }
    const int row = blk * 4 + (threadIdx.x >> 6);
    const int lane = threadIdx.x & 63;
    float v[8];
#pragma unroll
    for (int j = 0; j < 8; ++j) v[j] = cb[lane + 64 * j];
    const float* p = src + (size_t)row * DIM;
    for (int ip = 0; ip < np; ++ip) {
#pragma unroll
        for (int j = 0; j < 8; ++j) v[j] += p[lane + 64 * j];
        p += pstride;
    }
    float s1v = 0.f, s2v = 0.f;
#pragma unroll
    for (int j = 0; j < 8; ++j) { s1v += v[j]; s2v += v[j] * v[j]; }
#pragma unroll
    for (int off = 32; off; off >>= 1) {
        s1v += __shfl_xor(s1v, off, 64);
        s2v += __shfl_xor(s2v, off, 64);
    }
    const float mean = s1v * (1.0f / DIM);
    const float var = s2v * (1.0f / DIM) - mean * mean;
    const float rstd = rsqrtf(var + 1e-5f);
    ushort_t* q = dst + (size_t)row * DIM;
#pragma unroll
    for (int j = 0; j < 8; ++j) {
        const int c = lane + 64 * j;
        float y = (v[j] - mean) * rstd * g[c] + bta[c];
        q[c] = f2bf(fminf(fmaxf(y, 0.0f), 6.0f));
    }
}

// ---------------------------------------------------------------------------
// vplus = v + dwconv3x3 + bias, both branches in one launch
// ---------------------------------------------------------------------------
__device__ __forceinline__ void vplus_body(
    const ushort_t* __restrict__ vbuf, const float* __restrict__ lw,
    const float* __restrict__ lb, ushort_t* __restrict__ out,
    int lOW, int lL, int blk)
{
    const int idx = blk * 256 + threadIdx.x;
    const int c = idx & 255;
    const int pix = (idx >> 8) & ((1 << lL) - 1);
    const int b = idx >> (8 + lL);
    const int OW = 1 << lOW;
    const int y = pix >> lOW, x = pix & (OW - 1);
    float acc = lb[c];
#pragma unroll
    for (int dy = -1; dy <= 1; ++dy) {
        const int ny = y + dy;
        if ((unsigned)ny >= (unsigned)OW) continue;
#pragma unroll
        for (int dx = -1; dx <= 1; ++dx) {
            const int nx = x + dx;
            if ((unsigned)nx >= (unsigned)OW) continue;
            acc += bf2f(vbuf[(((unsigned)(b << lL) + ny * OW + nx) << 8) + c]) *
                   lw[c * 9 + (dy + 1) * 3 + (dx + 1)];
        }
    }
    out[idx] = f2bf(bf2f(vbuf[idx]) + acc);
}

__global__ __launch_bounds__(256) void vplus2_kernel(
    const ushort_t* v1, const float* w1, const float* b1, ushort_t* o1,
    const ushort_t* v2, const float* w2, const float* b2, ushort_t* o2)
{
    const int bid = blockIdx.x;
    if (bid < 2048) vplus_body(v1, w1, b1, o1, 4, 8, bid);
    else            vplus_body(v2, w2, b2, o2, 5, 10, bid - 2048);
}

// ---------------------------------------------------------------------------
// MFMA attention, all operands bf16 (Q pre-scaled by 0.125 in q-projection).
// ---------------------------------------------------------------------------
template <int L>
__global__ __launch_bounds__(256) void attn_mfma(
    const ushort_t* __restrict__ qbuf, const ushort_t* __restrict__ kbuf,
    const ushort_t* __restrict__ vbuf, ushort_t* __restrict__ xbuf,
    int hoff, int coff)
{
    constexpr int SP = L + 12;
    constexpr int NV = L / 64;
    __shared__ float S[16][SP];
    __shared__ float invs[16];
    __shared__ alignas(16) short Qs[16][72];
    __shared__ alignas(16) short KV[64][72];

    const int tid = threadIdx.x;
    const int qt = blockIdx.x;
    const int h = blockIdx.y;
    const int b = blockIdx.z;
    const int lane = tid & 63, wave = tid >> 6;
    const int l16 = lane & 15, quad = lane >> 4;

    {
        const int r = tid >> 4, d0 = (tid & 15) * 4;
        int qi = qt * 16 + r; if (qi > QN - 1) qi = QN - 1;
        *(s16x4*)&Qs[r][d0] = *(const s16x4*)(
            qbuf + ((unsigned)(b * QN + qi) * NHEAD + hoff + h) * HD + d0);
    }

    // ---- Phase A: S = Q K^T ----
    const int klr = tid >> 2, kd0 = (tid & 3) * 16;
    for (int l0 = 0; l0 < L; l0 += 64) {
        const unsigned src = (unsigned)(b * L + l0 + klr) * C2 + h * HD + kd0;
        const s16x8 x0 = *(const s16x8*)(kbuf + src);
        const s16x8 x1 = *(const s16x8*)(kbuf + src + 8);
        __syncthreads();
        *(s16x8*)&KV[klr][kd0] = x0;
        *(s16x8*)&KV[klr][kd0 + 8] = x1;
        __syncthreads();
        f32x4 sacc = (f32x4){0.f, 0.f, 0.f, 0.f};
#pragma unroll
        for (int c = 0; c < 2; ++c) {
            const s16x8 af = *(const s16x8*)&Qs[l16][c * 32 + quad * 8];
            const s16x8 bf = *(const s16x8*)&KV[wave * 16 + l16][c * 32 + quad * 8];
            sacc = __builtin_amdgcn_mfma_f32_16x16x32_bf16(af, bf, sacc, 0, 0, 0);
        }
        const int col = l0 + wave * 16 + l16;
#pragma unroll
        for (int r = 0; r < 4; ++r) S[quad * 4 + r][col] = sacc[r];
    }
    __syncthreads();

    // ---- Phase B: softmax ----
#pragma unroll
    for (int rr = 0; rr < 4; ++rr) {
        const int row = wave * 4 + rr;
        float v[NV];
#pragma unroll
        for (int k = 0; k < NV; ++k) v[k] = S[row][lane + 64 * k];
        float m = -1e30f;
#pragma unroll
        for (int k = 0; k < NV; ++k) m = fmaxf(m, v[k]);
#pragma unroll
        for (int off = 32; off; off >>= 1) m = fmaxf(m, __shfl_xor(m, off, 64));
        float s = 0.f;
#pragma unroll
        for (int k = 0; k < NV; ++k) {
            v[k] = __expf(v[k] - m);
            s += v[k];
        }
#pragma unroll
        for (int off = 32; off; off >>= 1) s += __shfl_xor(s, off, 64);
#pragma unroll
        for (int k = 0; k < NV; ++k) S[row][lane + 64 * k] = v[k];
        if (lane == 0) invs[row] = 1.0f / s;
    }

    // ---- Phase C: O = P V ----
    f32x4 oacc = (f32x4){0.f, 0.f, 0.f, 0.f};
    const int vl = tid >> 4, vd0 = (tid & 15) * 4;
    for (int l0 = 0; l0 < L; l0 += 64) {
        s16x4 vr[4];
#pragma unroll
        for (int p = 0; p < 4; ++p)
            vr[p] = *(const s16x4*)(
                vbuf + (unsigned)(b * L + l0 + p * 16 + vl) * C2 + h * HD + vd0);
        __syncthreads();
#pragma unroll
        for (int p = 0; p < 4; ++p) {
            const int ll = p * 16 + vl;
            KV[vd0 + 0][ll] = vr[p][0];
            KV[vd0 + 1][ll] = vr[p][1];
            KV[vd0 + 2][ll] = vr[p][2];
            KV[vd0 + 3][ll] = vr[p][3];
        }
        __syncthreads();
#pragma unroll
        for (int c = 0; c < 2; ++c) {
            const float4 p0 = *(const float4*)&S[l16][l0 + c * 32 + quad * 8];
            const float4 p1 = *(const float4*)&S[l16][l0 + c * 32 + quad * 8 + 4];
            const s16x8 af = pack8(p0, p1);
            const s16x8 bf = *(const s16x8*)&KV[wave * 16 + l16][c * 32 + quad * 8];
            oacc = __builtin_amdgcn_mfma_f32_16x16x32_bf16(af, bf, oacc, 0, 0, 0);
        }
    }

    const int dcol = wave * 16 + l16;
#pragma unroll
    for (int r = 0; r < 4; ++r) {
        const int q = quad * 4 + r;
        const int qi = qt * 16 + q;
        if (qi < QN) {
            const float val = oacc[r] * invs[q];
            const int flat = ((b * QN + qi) * NH2 + h) * HD + dcol;
            xbuf[(unsigned)(flat >> 8) * DIM + coff + (flat & 255)] = f2bf(val);
        }
    }
}

// ---------------------------------------------------------------------------
// Launcher
// ---------------------------------------------------------------------------
extern "C" void kernel_launch(void* const* d_in, const int* in_sizes, int n_in,
                              void* d_out, int out_size, void* d_ws, size_t ws_size,
                              hipStream_t stream)
{
    const float* query   = (const float*)d_in[0];
    const float* key     = (const float*)d_in[1];
    const float* value   = (const float*)d_in[2];
    const float* q_w     = (const float*)d_in[3];
    const float* sr1_1_w = (const float*)d_in[4];
    const float* sr1_1_b = (const float*)d_in[5];
    const float* n1_1_g  = (const float*)d_in[6];
    const float* n1_1_b  = (const float*)d_in[7];
    const float* sr1_2_w = (const float*)d_in[8];
    const float* sr1_2_b = (const float*)d_in[9];
    const float* n1_2_g  = (const float*)d_in[10];
    const float* n1_2_b  = (const float*)d_in[11];
    const float* sr2_1_w = (const float*)d_in[12];
    const float* sr2_1_b = (const float*)d_in[13];
    const float* n2_1_g  = (const float*)d_in[14];
    const float* n2_1_b  = (const float*)d_in[15];
    const float* sr2_2_w = (const float*)d_in[16];
    const float* sr2_2_b = (const float*)d_in[17];
    const float* n2_2_g  = (const float*)d_in[18];
    const float* n2_2_b  = (const float*)d_in[19];
    const float* k1_w    = (const float*)d_in[20];
    const float* v1_w    = (const float*)d_in[21];
    const float* k2_w    = (const float*)d_in[22];
    const float* v2_w    = (const float*)d_in[23];
    const float* lc1_w   = (const float*)d_in[24];
    const float* lc1_b   = (const float*)d_in[25];
    const float* lc2_w   = (const float*)d_in[26];
    const float* lc2_b   = (const float*)d_in[27];
    const float* proj_w  = (const float*)d_in[28];
    const float* proj_b  = (const float*)d_in[29];
    float* out = (float*)d_out;
    char* ws = (char*)d_ws;

    // --- workspace layout (bytes); total ~199 MB (d_ws is 256 MiB) ---
    ushort_t* IMGK = (ushort_t*)(ws + 0);            // 33.5 MB
    ushort_t* IMGV = (ushort_t*)(ws + 33554432);     // 33.5 MB
    float*    SCRK = (float*)(ws + 67108864);        // 33.5 MB fp32 partials
    float*    SCRV = (float*)(ws + 100663296);       // 33.5 MB
    ushort_t* WT1K = (ushort_t*)(ws + 134217728);    // 8.4 MB
    ushort_t* WT1V = (ushort_t*)(ws + 142606336);    // 8.4 MB
    ushort_t* WT2K = (ushort_t*)(ws + 150994944);    // 2.1 MB
    ushort_t* WT2V = (ushort_t*)(ws + 153092096);    // 2.1 MB
    ushort_t* KEY1 = (ushort_t*)(ws + 155189248);    // 2.1 MB
    ushort_t* VAL1 = (ushort_t*)(ws + 157286400);
    ushort_t* KEY2 = (ushort_t*)(ws + 159383552);    // 8.4 MB
    ushort_t* VAL2 = (ushort_t*)(ws + 167772160);
    ushort_t* QRYB = (ushort_t*)(ws + 176160768);    // 1600x512 bf16
    ushort_t* WQ   = (ushort_t*)(ws + 177799168);
    ushort_t* WK1  = (ushort_t*)(ws + 178323456);
    ushort_t* WV1  = (ushort_t*)(ws + 178585600);
    ushort_t* WK2  = (ushort_t*)(ws + 178847744);
    ushort_t* WV2  = (ushort_t*)(ws + 179109888);
    ushort_t* WP   = (ushort_t*)(ws + 179372032);
    ushort_t* QBUF = (ushort_t*)(ws + 179896320);
    ushort_t* XBUF = (ushort_t*)(ws + 181534720);
    ushort_t* K1   = (ushort_t*)(ws + 183173120);
    ushort_t* V1   = (ushort_t*)(ws + 184221696);
    ushort_t* VP1  = (ushort_t*)(ws + 185270272);
    ushort_t* K2   = (ushort_t*)(ws + 186318848);
    ushort_t* V2   = (ushort_t*)(ws + 190513152);
    ushort_t* VP2  = (ushort_t*)(ws + 194707456);    // ends 198,901,760

    // 1) all fp32->bf16 conversions (one launch)
    CPack cp;
    cp.c[0] = {key,   IMGK}; cp.c[1] = {value, IMGV}; cp.c[2] = {query, QRYB};
    cp.c[3] = {q_w,   WQ};   cp.c[4] = {k1_w,  WK1};  cp.c[5] = {v1_w,  WV1};
    cp.c[6] = {k2_w,  WK2};  cp.c[7] = {v2_w,  WV2};  cp.c[8] = {proj_w, WP};
    cp.bound[0] = 8192;  cp.bound[1] = 16384; cp.bound[2] = 16784;
    cp.bound[3] = 16912; cp.bound[4] = 16976; cp.bound[5] = 17040;
    cp.bound[6] = 17104; cp.bound[7] = 17168; cp.bound[8] = 17296;
    cvt_all<<<17296, 256, 0, stream>>>(cp);

    // 2) all 4 conv-weight transposes (one launch)
    WPack wp;
    wp.w[0] = {sr1_1_w, WT1K, 16, 4}; wp.w[1] = {sr1_2_w, WT1V, 16, 4};
    wp.w[2] = {sr2_1_w, WT2K, 4, 2};  wp.w[3] = {sr2_2_w, WT2V, 4, 2};
    wtrans4<<<2048, 256, 0, stream>>>(wp);

    // 3) conv1 (key+value), split-K z=8 (klen=1024) -> fp32 partials
    conv_gemm<<<1024, 256, 0, stream>>>(IMGK, WT1K, SCRK, IMGV, WT1V, SCRV,
                                        2048, 8192, 1024, 4, 2, 4);
    ln2_kernel<<<1024, 256, 0, stream>>>(KEY1, SCRK, sr1_1_b, n1_1_g, n1_1_b,
                                         VAL1, SCRV, sr1_2_b, n1_2_g, n1_2_b,
                                         1048576u, 8, 512);

    // 4) conv2 (key+value), z=2 (klen=1024)
    conv_gemm<<<1024, 256, 0, stream>>>(IMGK, WT2K, SCRK, IMGV, WT2V, SCRV,
                                        8192, 2048, 1024, 5, 1, 6);
    ln2_kernel<<<4096, 256, 0, stream>>>(KEY2, SCRK, sr2_1_b, n2_1_g, n2_1_b,
                                         VAL2, SCRV, sr2_2_b, n2_2_g, n2_2_b,
                                         4194304u, 2, 2048);

    // 5) merged projections: q (scale 0.125 folded), k1, v1, k2, v2
    PPack pp;
    pp.d[0] = {QRYB, WQ,  QBUF, 3, 0.125f};
    pp.d[1] = {KEY1, WK1, K1,   2, 1.0f};
    pp.d[2] = {VAL1, WV1, V1,   2, 1.0f};
    pp.d[3] = {KEY2, WK2, K2,   2, 1.0f};
    pp.d[4] = {VAL2, WV2, V2,   2, 1.0f};
    pp.bound[0] = 200; pp.bound[1] = 328; pp.bound[2] = 456; pp.bound[3] = 968;
    pp.bound[4] = 1480;
    proj_gemm<<<1480, 256, 0, stream>>>(pp);

    // 6) v + local dwconv (both branches)
    vplus2_kernel<<<10240, 256, 0, stream>>>(V1, lc1_w, lc1_b, VP1,
                                             V2, lc2_w, lc2_b, VP2);

    // 7) attention
    attn_mfma<256><<<dim3(13, 4, 8), 256, 0, stream>>>(QBUF, K1, VP1, XBUF, 0, 0);
    attn_mfma<1024><<<dim3(13, 4, 8), 256, 0, stream>>>(QBUF, K2, VP2, XBUF, 4, 256);

    // 8) final projection + bias -> fp32 out
    final_gemm<<<200, 256, 0, stream>>>(XBUF, WP, proj_b, out);
}